// Round 10
// baseline (1561.505 us; speedup 1.0000x reference)
//
#include <hip/hip_runtime.h>
#include <math.h>

#define B_ 64
#define S_ 128
#define F_ 62
#define D_ 256
#define H_ 4
#define L_ 6
#define NSUB_ 32
#define DFF_ 512
#define DH_ 128
#define DEPTH_ 32
#define MS_ (B_*S_)                 // 8192 rows
#define NEGV (-1000000000.0f)
#define SCALE_ 0.17677669529663687f // 1/sqrt(32)

typedef unsigned short u16;
typedef __attribute__((ext_vector_type(8))) short short8;
typedef __attribute__((ext_vector_type(4))) float f32x4;

// f32 -> bf16 round-to-nearest-even
__device__ __forceinline__ u16 f2b(float f){
  unsigned u = __float_as_uint(f);
  unsigned r = (u + 0x7fffu + ((u >> 16) & 1u)) >> 16;
  return (u16)r;
}
__device__ __forceinline__ float b2f(u16 v){
  return __uint_as_float((unsigned)v << 16);
}

__device__ __forceinline__ void glds16(const void* g, void* l){
  __builtin_amdgcn_global_load_lds(
      (const __attribute__((address_space(1))) unsigned int*)g,
      (__attribute__((address_space(3))) unsigned int*)l, 16, 0, 0);
}

// --------- grid barrier: system-scope atomics + fences, bounded spin --------
__device__ __forceinline__ void grid_barrier(unsigned* cnt, unsigned* gen){
  __syncthreads();
  if(threadIdx.x == 0){
    __threadfence_system();
    unsigned g = __hip_atomic_load(gen, __ATOMIC_RELAXED, __HIP_MEMORY_SCOPE_SYSTEM);
    unsigned a = __hip_atomic_fetch_add(cnt, 1u, __ATOMIC_ACQ_REL, __HIP_MEMORY_SCOPE_SYSTEM);
    if(a == gridDim.x - 1u){
      __hip_atomic_store(cnt, 0u, __ATOMIC_RELAXED, __HIP_MEMORY_SCOPE_SYSTEM);
      __hip_atomic_store(gen, g + 1u, __ATOMIC_RELEASE, __HIP_MEMORY_SCOPE_SYSTEM);
    } else {
      int spins = 0;
      while(__hip_atomic_load(gen, __ATOMIC_ACQUIRE, __HIP_MEMORY_SCOPE_SYSTEM) == g){
        __builtin_amdgcn_s_sleep(8);
        if(++spins > (1 << 20)) break;   // hang escape; should never trigger
      }
    }
    __threadfence_system();
  }
  __syncthreads();
}

// ------- adjm16 = bf16(adj + mask); distr16 = bf16(rescale(dist)*scale) -----
__global__ __launch_bounds__(256) void adjrescale_kernel(
    const float* __restrict__ adj, const float* __restrict__ dist,
    const float* __restrict__ maskb,
    u16* __restrict__ adjm16, u16* __restrict__ distr16){
  size_t i = (size_t)blockIdx.x*256 + threadIdx.x;
  int j = (int)(i & (S_-1));
  int b = (int)(i >> 14);            // S_*S_ = 16384
  const float e1 = 2.718281828459045f;
  distr16[i] = f2b((1.0f + e1) / (1.0f + expf(1.0f - dist[i])) * SCALE_);
  adjm16[i]  = f2b(adj[i] + maskb[b*S_ + j]);
}

// ------ all weight transposes in ONE dispatch: dst[l][n][k] = src[l][k][n] --
struct TD { const float* src; u16* dst; int K, N, L; };
struct TDs { TD d[11]; };
__global__ __launch_bounds__(256) void transpose_all_kernel(TDs a){
  const TD p = a.d[blockIdx.z];
  int n0 = blockIdx.x*32, k0 = blockIdx.y*32;
  if(n0 >= p.N || k0 >= p.K) return;
  __shared__ float tbuf[32][33];
  int tx = threadIdx.x, ty = threadIdx.y;   // 32 x 8
  for(int l = 0; l < p.L; l++){
    const float* src = p.src + (size_t)l*p.K*p.N;
    u16* dst = p.dst + (size_t)l*p.K*p.N;
    #pragma unroll
    for(int i = 0; i < 4; i++)
      tbuf[ty + i*8][tx] = src[(size_t)(k0 + ty + i*8)*p.N + n0 + tx];
    __syncthreads();
    #pragma unroll
    for(int i = 0; i < 4; i++)
      dst[(size_t)(n0 + ty + i*8)*p.K + k0 + tx] = f2b(tbuf[tx][ty + i*8]);
    __syncthreads();
  }
}

// --------- embed: h = relu(x @ emb_W + emb_b), K=62; also emits maskb -------
__global__ __launch_bounds__(256) void embed_kernel(const float* __restrict__ x,
    const float* __restrict__ W, const float* __restrict__ bias,
    float* __restrict__ h, u16* __restrict__ h_bf, float* __restrict__ maskb){
  __shared__ float xs[4][F_];
  int r0 = blockIdx.x*4;
  int t = threadIdx.x;
  if(t < 4*F_){ int rr = t / F_, ff = t - rr*F_; xs[rr][ff] = x[(size_t)(r0+rr)*F_ + ff]; }
  __syncthreads();
  if(t < 4){
    float s = 0.f;
    #pragma unroll
    for(int f = 0; f < F_; f++) s += xs[t][f];
    maskb[r0 + t] = (s == 0.0f) ? NEGV : 0.0f;
  }
  float b = bias[t];
  float a0=b, a1=b, a2=b, a3=b;
  for(int k=0; k<F_; k++){
    float w = W[k*D_ + t];
    a0 = fmaf(xs[0][k], w, a0);
    a1 = fmaf(xs[1][k], w, a1);
    a2 = fmaf(xs[2][k], w, a2);
    a3 = fmaf(xs[3][k], w, a3);
  }
  a0 = fmaxf(a0, 0.f); a1 = fmaxf(a1, 0.f); a2 = fmaxf(a2, 0.f); a3 = fmaxf(a3, 0.f);
  h[(size_t)(r0+0)*D_ + t] = a0;  h_bf[(size_t)(r0+0)*D_ + t] = f2b(a0);
  h[(size_t)(r0+1)*D_ + t] = a1;  h_bf[(size_t)(r0+1)*D_ + t] = f2b(a1);
  h[(size_t)(r0+2)*D_ + t] = a2;  h_bf[(size_t)(r0+2)*D_ + t] = f2b(a2);
  h[(size_t)(r0+3)*D_ + t] = a3;  h_bf[(size_t)(r0+3)*D_ + t] = f2b(a3);
}

// =================== bf16 MFMA GEMM (final GEMM only) =======================
struct MG {
  const u16* A; const u16* W; const float* bias; void* C;
  int lda, K, ldc, aofs, cofs;
};
struct MG6 { MG g[6]; };

template<int TM, bool OUTBF, int ACT>
__global__ __launch_bounds__(256) void mgemm_kernel(MG6 args){
  const MG p = args.g[blockIdx.z];
  __shared__ u16 As[TM*32];
  __shared__ u16 Bs[128*32];
  const int t    = threadIdx.x;
  const int lane = t & 63;
  const int w    = t >> 6;
  const int ln   = lane & 15;
  const int qd   = lane >> 4;
  const int mw   = (w & 1) * (TM/2);
  const int nw   = (w >> 1) * 64;
  const int m0   = blockIdx.x * TM;
  const int n0   = blockIdx.y * 128;
  constexpr int MI = TM/32;
  f32x4 acc[MI][4];
  #pragma unroll
  for(int i=0;i<MI;i++)
    #pragma unroll
    for(int j=0;j<4;j++) acc[i][j] = (f32x4){0.f,0.f,0.f,0.f};

  const int srow = t >> 2;
  const int sc8  = (t & 3) * 8;

  for(int k0 = 0; k0 < p.K; k0 += 32){
    __syncthreads();
    glds16(p.A + (size_t)(m0 + srow)*p.lda + p.aofs + k0 + sc8, As + t*8);
    if(TM == 128)
      glds16(p.A + (size_t)(m0 + 64 + srow)*p.lda + p.aofs + k0 + sc8, As + (t+256)*8);
    glds16(p.W + (size_t)(n0 + srow)*p.K + k0 + sc8, Bs + t*8);
    glds16(p.W + (size_t)(n0 + 64 + srow)*p.K + k0 + sc8, Bs + (t+256)*8);
    __syncthreads();

    short8 a[MI], b[4];
    #pragma unroll
    for(int i=0;i<MI;i++) a[i] = *(const short8*)&As[(mw + i*16 + ln)*32 + qd*8];
    #pragma unroll
    for(int j=0;j<4;j++)  b[j] = *(const short8*)&Bs[(nw + j*16 + ln)*32 + qd*8];
    #pragma unroll
    for(int i=0;i<MI;i++)
      #pragma unroll
      for(int j=0;j<4;j++)
        acc[i][j] = __builtin_amdgcn_mfma_f32_16x16x32_bf16(a[i], b[j], acc[i][j], 0, 0, 0);
  }

  #pragma unroll
  for(int i=0;i<MI;i++){
    #pragma unroll
    for(int j=0;j<4;j++){
      int col = n0 + nw + j*16 + ln;
      float bv = p.bias[col];
      int rowb = m0 + mw + i*16 + qd*4;
      #pragma unroll
      for(int r=0;r<4;r++){
        float v = acc[i][j][r] + bv;
        if(ACT == 1) v = fmaxf(v, 0.f);
        if(ACT == 2) v = 0.5f*v*(1.0f + erff(v*0.70710678118654752f));
        size_t idx = (size_t)(rowb + r)*p.ldc + p.cofs + col;
        if(OUTBF) ((u16*)p.C)[idx] = f2b(v);
        else      ((float*)p.C)[idx] = v;
      }
    }
  }
}

// ============================ mega-kernel bodies ============================
struct MegaArgs {
  float* h; u16* h_bf;
  u16 *o1, *o2;
  const u16 *adjm16, *distr16; const float* maskb;
  const u16 *wq1,*wk1,*wv1,*wo1,*wq2,*wk2,*wv2,*wo2,*wf1,*wf2;
  const float *bq1,*bk1,*bv1,*bo1,*bq2,*bk2,*bv2,*bo2,*bf1v,*bf2v,*g1,*be1,*g2,*be2;
  unsigned *cnt, *gen;
};

// ---- phase Q: one (b,head,branch) unit: QKV proj + attention -> o1/o2 ------
__device__ __forceinline__ void qkv_attn_body(u16* SH, int unit, int l, const MegaArgs& p){
  u16* As = SH;                      // [128][32]
  u16* Bs = SH + 4096;               // [96][32]  rows 0-31 Wq, 32-63 Wk, 64-95 Wv
  u16* Qs = SH + 7168;               // [128][40]
  u16* Ks = SH + 12288;              // [128][40]
  u16* Vt = SH + 17408;              // [32][136]
  u16* Ps = SH;                      // [128][136] alias (phase2)

  const int branch = unit & 1;
  const int bh = unit >> 1;
  const int b  = bh >> 2;
  const int hh = bh & 3;
  const u16* wqp = (branch ? p.wq2 : p.wq1) + (size_t)l*DH_*DH_ + (size_t)hh*32*DH_;
  const u16* wkp = (branch ? p.wk2 : p.wk1) + (size_t)l*DH_*DH_ + (size_t)hh*32*DH_;
  const u16* wvp = (branch ? p.wv2 : p.wv1) + (size_t)l*DH_*DH_ + (size_t)hh*32*DH_;
  const float* bqp = (branch ? p.bq2 : p.bq1) + (size_t)l*DH_ + hh*32;
  const float* bkp = (branch ? p.bk2 : p.bk1) + (size_t)l*DH_ + hh*32;
  const float* bvp = (branch ? p.bv2 : p.bv1) + (size_t)l*DH_ + hh*32;
  const int t = threadIdx.x;
  const int w = t >> 6, lane = t & 63;
  const int ln = lane & 15, qd = lane >> 4;
  const size_t rowbase = (size_t)b * S_;
  const int srow = t >> 2, sc8 = (t & 3) * 8;
  const int mbase = w * 32;

  // prefetch score-fixup operands (bf16) + mask (hidden behind phase-1 MFMAs)
  u16 fixu[2][4][8];
  {
    const u16* basep = (branch ? p.distr16 : p.adjm16) + rowbase*S_;
    #pragma unroll
    for(int mt = 0; mt < 2; mt++)
      #pragma unroll
      for(int r = 0; r < 4; r++){
        int row = mbase + mt*16 + qd*4 + r;
        #pragma unroll
        for(int nt = 0; nt < 8; nt++)
          fixu[mt][r][nt] = basep[(size_t)row*S_ + nt*16 + ln];
      }
  }
  float mskv[8];
  if(branch){
    #pragma unroll
    for(int nt = 0; nt < 8; nt++) mskv[nt] = p.maskb[rowbase + nt*16 + ln];
  }

  // ---- phase 1: QKV projection ----
  f32x4 acc[2][6];
  #pragma unroll
  for(int i=0;i<2;i++)
    #pragma unroll
    for(int j=0;j<6;j++) acc[i][j] = (f32x4){0.f,0.f,0.f,0.f};

  for(int k0 = 0; k0 < DH_; k0 += 32){
    __syncthreads();
    glds16(p.h_bf + (rowbase + srow)*D_ + branch*DH_ + k0 + sc8, As + t*8);
    glds16(p.h_bf + (rowbase + 64 + srow)*D_ + branch*DH_ + k0 + sc8, As + (t+256)*8);
    {
      int r = t >> 2;
      const u16* wp = (r < 32) ? wqp : wkp;
      glds16(wp + (size_t)(r & 31)*DH_ + k0 + sc8, Bs + t*8);
    }
    if(t < 128){
      int c = 256 + t;
      glds16(wvp + (size_t)((c>>2) - 64)*DH_ + k0 + (c&3)*8, Bs + c*8);
    }
    __syncthreads();
    short8 av[2];
    #pragma unroll
    for(int mt = 0; mt < 2; mt++)
      av[mt] = *(const short8*)&As[(w*32 + mt*16 + ln)*32 + qd*8];
    #pragma unroll
    for(int nt = 0; nt < 6; nt++){
      short8 bv = *(const short8*)&Bs[(nt*16 + ln)*32 + qd*8];
      #pragma unroll
      for(int mt = 0; mt < 2; mt++)
        acc[mt][nt] = __builtin_amdgcn_mfma_f32_16x16x32_bf16(av[mt], bv, acc[mt][nt], 0, 0, 0);
    }
  }

  #pragma unroll
  for(int mt = 0; mt < 2; mt++){
    int rb = w*32 + mt*16 + qd*4;
    #pragma unroll
    for(int j = 0; j < 2; j++){
      int d = j*16 + ln;
      float bq_ = bqp[d], bk_ = bkp[d], bv_ = bvp[d];
      #pragma unroll
      for(int r = 0; r < 4; r++){
        Qs[(rb+r)*40 + d]   = f2b(acc[mt][j][r]   + bq_);
        Ks[(rb+r)*40 + d]   = f2b(acc[mt][2+j][r] + bk_);
        Vt[d*136 + rb + r]  = f2b(acc[mt][4+j][r] + bv_);
      }
    }
  }
  __syncthreads();

  // ---- phase 2: attention ----
  short8 qf[2];
  #pragma unroll
  for(int mt = 0; mt < 2; mt++)
    qf[mt] = *(const short8*)&Qs[(mbase + mt*16 + ln)*40 + qd*8];
  short8 kf[8];
  #pragma unroll
  for(int nt = 0; nt < 8; nt++)
    kf[nt] = *(const short8*)&Ks[(nt*16 + ln)*40 + qd*8];
  __syncthreads();

  f32x4 sc[2][8];
  #pragma unroll
  for(int mt = 0; mt < 2; mt++)
    #pragma unroll
    for(int nt = 0; nt < 8; nt++)
      sc[mt][nt] = __builtin_amdgcn_mfma_f32_16x16x32_bf16(
          qf[mt], kf[nt], (f32x4){0.f,0.f,0.f,0.f}, 0, 0, 0);

  #pragma unroll
  for(int mt = 0; mt < 2; mt++){
    #pragma unroll
    for(int r = 0; r < 4; r++){
      #pragma unroll
      for(int nt = 0; nt < 8; nt++){
        float g = b2f(fixu[mt][r][nt]);
        float v;
        if(branch == 0) v = sc[mt][nt][r]*SCALE_ + g;   // adjm has mask folded
        else            v = fmaxf(sc[mt][nt][r], 0.f)*g + mskv[nt];
        sc[mt][nt][r] = v;
      }
    }
  }

  #pragma unroll
  for(int mt = 0; mt < 2; mt++){
    #pragma unroll
    for(int r = 0; r < 4; r++){
      float m = -3.4e38f;
      #pragma unroll
      for(int nt = 0; nt < 8; nt++) m = fmaxf(m, sc[mt][nt][r]);
      m = fmaxf(m, __shfl_xor(m, 1));
      m = fmaxf(m, __shfl_xor(m, 2));
      m = fmaxf(m, __shfl_xor(m, 4));
      m = fmaxf(m, __shfl_xor(m, 8));
      float sum = 0.f;
      float e[8];
      #pragma unroll
      for(int nt = 0; nt < 8; nt++){ e[nt] = __expf(sc[mt][nt][r] - m); sum += e[nt]; }
      sum += __shfl_xor(sum, 1);
      sum += __shfl_xor(sum, 2);
      sum += __shfl_xor(sum, 4);
      sum += __shfl_xor(sum, 8);
      float inv = 1.0f / sum;
      int row = mbase + mt*16 + qd*4 + r;
      #pragma unroll
      for(int nt = 0; nt < 8; nt++) Ps[row*136 + nt*16 + ln] = f2b(e[nt] * inv);
    }
  }
  // no barrier: each wave reads only its own P rows

  f32x4 oacc[2][2];
  #pragma unroll
  for(int mt = 0; mt < 2; mt++)
    #pragma unroll
    for(int n2 = 0; n2 < 2; n2++) oacc[mt][n2] = (f32x4){0.f,0.f,0.f,0.f};
  #pragma unroll
  for(int kk = 0; kk < 4; kk++){
    short8 pa[2], vb[2];
    #pragma unroll
    for(int mt = 0; mt < 2; mt++)
      pa[mt] = *(const short8*)&Ps[(mbase + mt*16 + ln)*136 + kk*32 + qd*8];
    #pragma unroll
    for(int n2 = 0; n2 < 2; n2++)
      vb[n2] = *(const short8*)&Vt[(n2*16 + ln)*136 + kk*32 + qd*8];
    #pragma unroll
    for(int mt = 0; mt < 2; mt++)
      #pragma unroll
      for(int n2 = 0; n2 < 2; n2++)
        oacc[mt][n2] = __builtin_amdgcn_mfma_f32_16x16x32_bf16(pa[mt], vb[n2], oacc[mt][n2], 0, 0, 0);
  }

  u16* Og = branch ? p.o2 : p.o1;
  #pragma unroll
  for(int mt = 0; mt < 2; mt++){
    #pragma unroll
    for(int n2 = 0; n2 < 2; n2++){
      #pragma unroll
      for(int r = 0; r < 4; r++){
        int row = mbase + mt*16 + qd*4 + r;
        int d   = n2*16 + ln;
        Og[(rowbase + row)*DH_ + hh*DEPTH_ + d] = f2b(oacc[mt][n2][r]);
      }
    }
  }
}

// ---- phase T: 16 rows: oproj+res+LN1 + FFN1+gelu + FFN2+res+LN2 ------------
// 4 waves; wave owns 64 cols (oproj/ffn2) / 64 cols per 256-half (ffn1).
__device__ __forceinline__ void tail_body(u16* SH, int m0, int l, const MegaArgs& p){
  u16* X1 = SH;                          // [16][264] LN1 out bf16
  u16* X2 = SH + 4224;                   // [16][264] gelu(ffn1) half
  float* redS = (float*)(SH + 8448);     // [4][16]
  float* redQ = redS + 64;               // [4][16]
  const int t = threadIdx.x;
  const int w = t >> 6, lane = t & 63;
  const int ln = lane & 15, qd = lane >> 4;
  const int branch = w >> 1;
  const int c0 = w * 64;                 // global col base (oproj out & ffn2 out)
  const int bc0 = (w & 1) * 64;          // col base within branch
  const u16* Ao = branch ? p.o2 : p.o1;
  const u16* Wo = (branch ? p.wo2 : p.wo1) + (size_t)l*DH_*DH_;
  const float* bo = (branch ? p.bo2 : p.bo1) + (size_t)l*DH_;
  const u16* w1 = p.wf1 + (size_t)l*D_*DFF_;
  const u16* w2 = p.wf2 + (size_t)l*DFF_*D_;
  const float* bfv1 = p.bf1v + (size_t)l*DFF_;
  const float* bfv2 = p.bf2v + (size_t)l*D_;
  const float* g1v = p.g1 + (size_t)l*D_;
  const float* be1v = p.be1 + (size_t)l*D_;
  const float* g2v = p.g2 + (size_t)l*D_;
  const float* be2v = p.be2 + (size_t)l*D_;

  // ---- phase A: out-projection (16 rows x 64 cols per wave) ----
  f32x4 y[4];
  #pragma unroll
  for(int nt=0;nt<4;nt++) y[nt] = (f32x4){0.f,0.f,0.f,0.f};
  #pragma unroll
  for(int k0 = 0; k0 < DH_; k0 += 32){
    short8 af = *(const short8*)(Ao + (size_t)(m0+ln)*DH_ + k0 + qd*8);
    #pragma unroll
    for(int nt=0;nt<4;nt++){
      short8 bfr = *(const short8*)(Wo + (size_t)(bc0+nt*16+ln)*DH_ + k0 + qd*8);
      y[nt] = __builtin_amdgcn_mfma_f32_16x16x32_bf16(af, bfr, y[nt], 0, 0, 0);
    }
  }
  float sS[4] = {}, sQ[4] = {};
  #pragma unroll
  for(int nt=0;nt<4;nt++){
    int col = c0 + nt*16 + ln;
    float bv = bo[bc0 + nt*16 + ln];
    #pragma unroll
    for(int r=0;r<4;r++){
      float v = y[nt][r] + bv + p.h[(size_t)(m0+qd*4+r)*D_ + col];
      y[nt][r] = v;
      sS[r] += v; sQ[r] += v*v;
    }
  }
  #pragma unroll
  for(int r=0;r<4;r++){
    float a = sS[r], bq = sQ[r];
    a += __shfl_xor(a,1); a += __shfl_xor(a,2); a += __shfl_xor(a,4); a += __shfl_xor(a,8);
    bq += __shfl_xor(bq,1); bq += __shfl_xor(bq,2); bq += __shfl_xor(bq,4); bq += __shfl_xor(bq,8);
    sS[r] = a; sQ[r] = bq;
  }
  if(ln == 0){
    #pragma unroll
    for(int r=0;r<4;r++){ redS[w*16 + qd*4+r] = sS[r]; redQ[w*16 + qd*4+r] = sQ[r]; }
  }
  __syncthreads();
  float mu[4], iv[4];
  #pragma unroll
  for(int r=0;r<4;r++){
    int row = qd*4 + r;
    float s = redS[row] + redS[16+row] + redS[32+row] + redS[48+row];
    float q = redQ[row] + redQ[16+row] + redQ[32+row] + redQ[48+row];
    float m_ = s * (1.0f/D_);
    mu[r] = m_;
    iv[r] = rsqrtf(q*(1.0f/D_) - m_*m_ + 1e-6f);
  }
  #pragma unroll
  for(int nt=0;nt<4;nt++){
    int col = c0 + nt*16 + ln;
    float gg = g1v[col], bb = be1v[col];
    #pragma unroll
    for(int r=0;r<4;r++){
      float yy = (y[nt][r] - mu[r]) * iv[r] * gg + bb;
      y[nt][r] = yy;                     // LN1 out = LN2 residual
      X1[(qd*4+r)*264 + col] = f2b(yy);
    }
  }
  __syncthreads();

  // ---- FFN in two 256-col halves ----
  f32x4 f2a[4];
  #pragma unroll
  for(int nt=0;nt<4;nt++) f2a[nt] = (f32x4){0.f,0.f,0.f,0.f};

  for(int hf = 0; hf < 2; hf++){
    // FFN1 half + GELU: wave owns local cols w*64..w*64+63 of this half
    f32x4 f1[4];
    #pragma unroll
    for(int nt=0;nt<4;nt++) f1[nt] = (f32x4){0.f,0.f,0.f,0.f};
    for(int k0 = 0; k0 < D_; k0 += 32){
      short8 a0 = *(const short8*)&X1[ln*264 + k0 + qd*8];
      #pragma unroll
      for(int nt=0;nt<4;nt++){
        short8 bfr = *(const short8*)(w1 + (size_t)(hf*256 + w*64 + nt*16+ln)*D_ + k0 + qd*8);
        f1[nt] = __builtin_amdgcn_mfma_f32_16x16x32_bf16(a0, bfr, f1[nt], 0, 0, 0);
      }
    }
    #pragma unroll
    for(int nt=0;nt<4;nt++){
      int lcol = w*64 + nt*16 + ln;
      float bv = bfv1[hf*256 + lcol];
      #pragma unroll
      for(int r=0;r<4;r++){
        float v = f1[nt][r] + bv;
        v = 0.5f*v*(1.0f + erff(v*0.70710678118654752f));
        X2[(qd*4+r)*264 + lcol] = f2b(v);
      }
    }
    __syncthreads();
    // FFN2 partial over this half's K range
    for(int k0 = 0; k0 < 256; k0 += 32){
      short8 a0 = *(const short8*)&X2[ln*264 + k0 + qd*8];
      #pragma unroll
      for(int nt=0;nt<4;nt++){
        short8 bfr = *(const short8*)(w2 + (size_t)(c0+nt*16+ln)*DFF_ + hf*256 + k0 + qd*8);
        f2a[nt] = __builtin_amdgcn_mfma_f32_16x16x32_bf16(a0, bfr, f2a[nt], 0, 0, 0);
      }
    }
    __syncthreads();
  }

  // ---- FFN2 bias + residual + LN2 ----
  float sS2[4] = {}, sQ2[4] = {};
  #pragma unroll
  for(int nt=0;nt<4;nt++){
    int col = c0 + nt*16 + ln;
    float bv = bfv2[col];
    #pragma unroll
    for(int r=0;r<4;r++){
      float v = f2a[nt][r] + bv + y[nt][r];
      f2a[nt][r] = v;
      sS2[r] += v; sQ2[r] += v*v;
    }
  }
  #pragma unroll
  for(int r=0;r<4;r++){
    float a = sS2[r], bq = sQ2[r];
    a += __shfl_xor(a,1); a += __shfl_xor(a,2); a += __shfl_xor(a,4); a += __shfl_xor(a,8);
    bq += __shfl_xor(bq,1); bq += __shfl_xor(bq,2); bq += __shfl_xor(bq,4); bq += __shfl_xor(bq,8);
    sS2[r] = a; sQ2[r] = bq;
  }
  if(ln == 0){
    #pragma unroll
    for(int r=0;r<4;r++){ redS[w*16 + qd*4+r] = sS2[r]; redQ[w*16 + qd*4+r] = sQ2[r]; }
  }
  __syncthreads();
  #pragma unroll
  for(int r=0;r<4;r++){
    int row = qd*4 + r;
    float s = redS[row] + redS[16+row] + redS[32+row] + redS[48+row];
    float q = redQ[row] + redQ[16+row] + redQ[32+row] + redQ[48+row];
    float m_ = s * (1.0f/D_);
    mu[r] = m_;
    iv[r] = rsqrtf(q*(1.0f/D_) - m_*m_ + 1e-6f);
  }
  #pragma unroll
  for(int nt=0;nt<4;nt++){
    int col = c0 + nt*16 + ln;
    float gg = g2v[col], bb = be2v[col];
    #pragma unroll
    for(int r=0;r<4;r++){
      float yy = (f2a[nt][r] - mu[r]) * iv[r] * gg + bb;
      size_t idx = (size_t)(m0 + qd*4 + r)*D_ + col;
      p.h[idx] = yy;
      p.h_bf[idx] = f2b(yy);
    }
  }
}

// ---- mega kernel v2: 512 blocks (2/CU co-resident), 2 waves/SIMD ----------
__global__ __launch_bounds__(256, 2) void mega_kernel(MegaArgs p){
  __shared__ u16 SH[21760];          // 43.5 KB; 2 blocks/CU = 87 KB <= 160 KB
  for(int l = 0; l < L_; l++){
    qkv_attn_body(SH, blockIdx.x, l, p);
    grid_barrier(p.cnt, p.gen);
    tail_body(SH, blockIdx.x*16, l, p);
    if(l < L_-1) grid_barrier(p.cnt, p.gen);
  }
}

// ---------------- pooled[b,n,:] = (amm[b,n,:] @ h[b]) / sum_atoms -----------
__global__ __launch_bounds__(256) void pool_kernel(
    const float* __restrict__ amm, const float* __restrict__ sum_atoms,
    const float* __restrict__ h, u16* __restrict__ pooled_bf)
{
  __shared__ float as[S_];
  int bn = blockIdx.x;
  int b  = bn >> 5;
  int t  = threadIdx.x;
  if(t < S_) as[t] = amm[(size_t)bn*S_ + t];
  __syncthreads();
  float acc = 0.f;
  const float* hb = h + (size_t)b*S_*D_ + t;
  #pragma unroll 4
  for(int s = 0; s < S_; s++) acc = fmaf(as[s], hb[(size_t)s*D_], acc);
  pooled_bf[(size_t)bn*D_ + t] = f2b(acc / sum_atoms[bn]);
}

// ============================ host-side launcher ============================
extern "C" void kernel_launch(void* const* d_in, const int* in_sizes, int n_in,
                              void* d_out, int out_size, void* d_ws, size_t ws_size,
                              hipStream_t stream)
{
  const float* x     = (const float*)d_in[0];
  const float* adj   = (const float*)d_in[1];
  const float* dist  = (const float*)d_in[2];
  const float* amm   = (const float*)d_in[3];
  const float* sum_a = (const float*)d_in[4];
  const float* embW  = (const float*)d_in[5];
  const float* embB  = (const float*)d_in[6];
  const float* globW = (const float*)d_in[7];
  const float* globB = (const float*)d_in[8];
  const float* Wq1 = (const float*)d_in[9],  *Wk1 = (const float*)d_in[10],
             *Wv1 = (const float*)d_in[11], *Wo1 = (const float*)d_in[12],
             *Wq2 = (const float*)d_in[13], *Wk2 = (const float*)d_in[14],
             *Wv2 = (const float*)d_in[15], *Wo2 = (const float*)d_in[16];
  const float* bq1 = (const float*)d_in[17], *bk1 = (const float*)d_in[18],
             *bv1 = (const float*)d_in[19], *bo1 = (const float*)d_in[20],
             *bq2 = (const float*)d_in[21], *bk2 = (const float*)d_in[22],
             *bv2 = (const float*)d_in[23], *bo2 = (const float*)d_in[24];
  const float* Wf1 = (const float*)d_in[25], *bf1 = (const float*)d_in[26],
             *Wf2 = (const float*)d_in[27], *bf2 = (const float*)d_in[28],
             *g1  = (const float*)d_in[29], *be1 = (const float*)d_in[30],
             *g2  = (const float*)d_in[31], *be2 = (const float*)d_in[32];

  float* wsf = (float*)d_ws;
  float* h     = wsf; wsf += (size_t)MS_*D_;
  float* maskb = wsf; wsf += MS_;
  unsigned* barrier = (unsigned*)wsf; wsf += 64;   // cnt, gen (+ pad)
  // bf16 region
  u16* bb = (u16*)wsf;
  u16* adjm16  = bb; bb += (size_t)B_*S_*S_;
  u16* distr16 = bb; bb += (size_t)B_*S_*S_;
  u16* o1_bf   = bb; bb += (size_t)MS_*DH_;
  u16* o2_bf   = bb; bb += (size_t)MS_*DH_;
  u16* h_bf    = bb; bb += (size_t)MS_*D_;
  u16* pooled_bf = bb; bb += (size_t)B_*NSUB_*D_;
  u16* globWt  = bb; bb += (size_t)D_*D_;
  u16* wq1t = bb; bb += (size_t)L_*DH_*DH_;
  u16* wk1t = bb; bb += (size_t)L_*DH_*DH_;
  u16* wv1t = bb; bb += (size_t)L_*DH_*DH_;
  u16* wo1t = bb; bb += (size_t)L_*DH_*DH_;
  u16* wq2t = bb; bb += (size_t)L_*DH_*DH_;
  u16* wk2t = bb; bb += (size_t)L_*DH_*DH_;
  u16* wv2t = bb; bb += (size_t)L_*DH_*DH_;
  u16* wo2t = bb; bb += (size_t)L_*DH_*DH_;
  u16* wf1t = bb; bb += (size_t)L_*D_*DFF_;       // [L][512][256]
  u16* wf2t = bb; bb += (size_t)L_*DFF_*D_;       // [L][256][512]

  hipMemsetAsync(barrier, 0, 16, stream);
  embed_kernel<<<MS_/4, 256, 0, stream>>>(x, embW, embB, h, h_bf, maskb);
  adjrescale_kernel<<<(B_*S_*S_)/256, 256, 0, stream>>>(adj, dist, maskb, adjm16, distr16);
  {
    TDs td;
    const float* S8[8] = {Wq1, Wk1, Wv1, Wo1, Wq2, Wk2, Wv2, Wo2};
    u16* D8[8] = {wq1t, wk1t, wv1t, wo1t, wq2t, wk2t, wv2t, wo2t};
    for(int i = 0; i < 8; i++) td.d[i] = {S8[i], D8[i], DH_, DH_, L_};
    td.d[8]  = {Wf1, wf1t, D_, DFF_, L_};
    td.d[9]  = {Wf2, wf2t, DFF_, D_, L_};
    td.d[10] = {globW, globWt, D_, D_, 1};
    transpose_all_kernel<<<dim3(16,16,11), dim3(32,8), 0, stream>>>(td);
  }

  MegaArgs ma;
  ma.h = h; ma.h_bf = h_bf;
  ma.o1 = o1_bf; ma.o2 = o2_bf;
  ma.adjm16 = adjm16; ma.distr16 = distr16; ma.maskb = maskb;
  ma.wq1 = wq1t; ma.wk1 = wk1t; ma.wv1 = wv1t; ma.wo1 = wo1t;
  ma.wq2 = wq2t; ma.wk2 = wk2t; ma.wv2 = wv2t; ma.wo2 = wo2t;
  ma.wf1 = wf1t; ma.wf2 = wf2t;
  ma.bq1 = bq1; ma.bk1 = bk1; ma.bv1 = bv1; ma.bo1 = bo1;
  ma.bq2 = bq2; ma.bk2 = bk2; ma.bv2 = bv2; ma.bo2 = bo2;
  ma.bf1v = bf1; ma.bf2v = bf2;
  ma.g1 = g1; ma.be1 = be1; ma.g2 = g2; ma.be2 = be2;
  ma.cnt = barrier; ma.gen = barrier + 1;
  mega_kernel<<<512, 256, 0, stream>>>(ma);

  pool_kernel<<<B_*NSUB_, 256, 0, stream>>>(amm, sum_a, h, pooled_bf);
  // final: relu(pooled @ glob_W + glob_b), M=2048 N=256 K=256
  {
    MG6 a;
    a.g[0].A = pooled_bf; a.g[0].W = globWt;
    a.g[0].bias = globB; a.g[0].C = (float*)d_out;
    a.g[0].lda = D_; a.g[0].K = D_; a.g[0].ldc = D_;
    a.g[0].aofs = 0; a.g[0].cofs = 0;
    mgemm_kernel<64,false,1><<<dim3((B_*NSUB_)/64, D_/128, 1), 256, 0, stream>>>(a);
  }
}

// Round 11
// 434.448 us; speedup vs baseline: 3.5942x; 3.5942x over previous
//
#include <hip/hip_runtime.h>
#include <math.h>

#define B_ 64
#define S_ 128
#define F_ 62
#define D_ 256
#define H_ 4
#define L_ 6
#define NSUB_ 32
#define DFF_ 512
#define DH_ 128
#define DEPTH_ 32
#define MS_ (B_*S_)                 // 8192 rows
#define NEGV (-1000000000.0f)
#define SCALE_ 0.17677669529663687f // 1/sqrt(32)

typedef unsigned short u16;
typedef __attribute__((ext_vector_type(8))) short short8;
typedef __attribute__((ext_vector_type(4))) float f32x4;

// f32 -> bf16 round-to-nearest-even
__device__ __forceinline__ u16 f2b(float f){
  unsigned u = __float_as_uint(f);
  unsigned r = (u + 0x7fffu + ((u >> 16) & 1u)) >> 16;
  return (u16)r;
}
__device__ __forceinline__ float b2f(u16 v){
  return __uint_as_float((unsigned)v << 16);
}

__device__ __forceinline__ void glds16(const void* g, void* l){
  __builtin_amdgcn_global_load_lds(
      (const __attribute__((address_space(1))) unsigned int*)g,
      (__attribute__((address_space(3))) unsigned int*)l, 16, 0, 0);
}

// ------- adjm16 = bf16(adj + mask); distr16 = bf16(rescale(dist)*scale) -----
__global__ __launch_bounds__(256) void adjrescale_kernel(
    const float* __restrict__ adj, const float* __restrict__ dist,
    const float* __restrict__ maskb,
    u16* __restrict__ adjm16, u16* __restrict__ distr16){
  size_t i = (size_t)blockIdx.x*256 + threadIdx.x;
  int j = (int)(i & (S_-1));
  int b = (int)(i >> 14);            // S_*S_ = 16384
  const float e1 = 2.718281828459045f;
  distr16[i] = f2b((1.0f + e1) / (1.0f + expf(1.0f - dist[i])) * SCALE_);
  adjm16[i]  = f2b(adj[i] + maskb[b*S_ + j]);
}

// ------ all weight transposes in ONE dispatch: dst[l][n][k] = src[l][k][n] --
struct TD { const float* src; u16* dst; int K, N, L; };
struct TDs { TD d[11]; };
__global__ __launch_bounds__(256) void transpose_all_kernel(TDs a){
  const TD p = a.d[blockIdx.z];
  int n0 = blockIdx.x*32, k0 = blockIdx.y*32;
  if(n0 >= p.N || k0 >= p.K) return;
  __shared__ float tbuf[32][33];
  int tx = threadIdx.x, ty = threadIdx.y;   // 32 x 8
  for(int l = 0; l < p.L; l++){
    const float* src = p.src + (size_t)l*p.K*p.N;
    u16* dst = p.dst + (size_t)l*p.K*p.N;
    #pragma unroll
    for(int i = 0; i < 4; i++)
      tbuf[ty + i*8][tx] = src[(size_t)(k0 + ty + i*8)*p.N + n0 + tx];
    __syncthreads();
    #pragma unroll
    for(int i = 0; i < 4; i++)
      dst[(size_t)(n0 + ty + i*8)*p.K + k0 + tx] = f2b(tbuf[tx][ty + i*8]);
    __syncthreads();
  }
}

// --------- embed: h = relu(x @ emb_W + emb_b), K=62; also emits maskb -------
__global__ __launch_bounds__(256) void embed_kernel(const float* __restrict__ x,
    const float* __restrict__ W, const float* __restrict__ bias,
    float* __restrict__ h, u16* __restrict__ h_bf, float* __restrict__ maskb){
  __shared__ float xs[4][F_];
  int r0 = blockIdx.x*4;
  int t = threadIdx.x;
  if(t < 4*F_){ int rr = t / F_, ff = t - rr*F_; xs[rr][ff] = x[(size_t)(r0+rr)*F_ + ff]; }
  __syncthreads();
  if(t < 4){
    float s = 0.f;
    #pragma unroll
    for(int f = 0; f < F_; f++) s += xs[t][f];
    maskb[r0 + t] = (s == 0.0f) ? NEGV : 0.0f;
  }
  float b = bias[t];
  float a0=b, a1=b, a2=b, a3=b;
  for(int k=0; k<F_; k++){
    float w = W[k*D_ + t];
    a0 = fmaf(xs[0][k], w, a0);
    a1 = fmaf(xs[1][k], w, a1);
    a2 = fmaf(xs[2][k], w, a2);
    a3 = fmaf(xs[3][k], w, a3);
  }
  a0 = fmaxf(a0, 0.f); a1 = fmaxf(a1, 0.f); a2 = fmaxf(a2, 0.f); a3 = fmaxf(a3, 0.f);
  h[(size_t)(r0+0)*D_ + t] = a0;  h_bf[(size_t)(r0+0)*D_ + t] = f2b(a0);
  h[(size_t)(r0+1)*D_ + t] = a1;  h_bf[(size_t)(r0+1)*D_ + t] = f2b(a1);
  h[(size_t)(r0+2)*D_ + t] = a2;  h_bf[(size_t)(r0+2)*D_ + t] = f2b(a2);
  h[(size_t)(r0+3)*D_ + t] = a3;  h_bf[(size_t)(r0+3)*D_ + t] = f2b(a3);
}

// =================== bf16 MFMA GEMM (final GEMM only) =======================
struct MG {
  const u16* A; const u16* W; const float* bias; void* C;
  int lda, K, ldc, aofs, cofs;
};
struct MG6 { MG g[6]; };

template<int TM, bool OUTBF, int ACT>
__global__ __launch_bounds__(256) void mgemm_kernel(MG6 args){
  const MG p = args.g[blockIdx.z];
  __shared__ u16 As[TM*32];
  __shared__ u16 Bs[128*32];
  const int t    = threadIdx.x;
  const int lane = t & 63;
  const int w    = t >> 6;
  const int ln   = lane & 15;
  const int qd   = lane >> 4;
  const int mw   = (w & 1) * (TM/2);
  const int nw   = (w >> 1) * 64;
  const int m0   = blockIdx.x * TM;
  const int n0   = blockIdx.y * 128;
  constexpr int MI = TM/32;
  f32x4 acc[MI][4];
  #pragma unroll
  for(int i=0;i<MI;i++)
    #pragma unroll
    for(int j=0;j<4;j++) acc[i][j] = (f32x4){0.f,0.f,0.f,0.f};

  const int srow = t >> 2;
  const int sc8  = (t & 3) * 8;

  for(int k0 = 0; k0 < p.K; k0 += 32){
    __syncthreads();
    glds16(p.A + (size_t)(m0 + srow)*p.lda + p.aofs + k0 + sc8, As + t*8);
    if(TM == 128)
      glds16(p.A + (size_t)(m0 + 64 + srow)*p.lda + p.aofs + k0 + sc8, As + (t+256)*8);
    glds16(p.W + (size_t)(n0 + srow)*p.K + k0 + sc8, Bs + t*8);
    glds16(p.W + (size_t)(n0 + 64 + srow)*p.K + k0 + sc8, Bs + (t+256)*8);
    __syncthreads();

    short8 a[MI], b[4];
    #pragma unroll
    for(int i=0;i<MI;i++) a[i] = *(const short8*)&As[(mw + i*16 + ln)*32 + qd*8];
    #pragma unroll
    for(int j=0;j<4;j++)  b[j] = *(const short8*)&Bs[(nw + j*16 + ln)*32 + qd*8];
    #pragma unroll
    for(int i=0;i<MI;i++)
      #pragma unroll
      for(int j=0;j<4;j++)
        acc[i][j] = __builtin_amdgcn_mfma_f32_16x16x32_bf16(a[i], b[j], acc[i][j], 0, 0, 0);
  }

  #pragma unroll
  for(int i=0;i<MI;i++){
    #pragma unroll
    for(int j=0;j<4;j++){
      int col = n0 + nw + j*16 + ln;
      float bv = p.bias[col];
      int rowb = m0 + mw + i*16 + qd*4;
      #pragma unroll
      for(int r=0;r<4;r++){
        float v = acc[i][j][r] + bv;
        if(ACT == 1) v = fmaxf(v, 0.f);
        if(ACT == 2) v = 0.5f*v*(1.0f + erff(v*0.70710678118654752f));
        size_t idx = (size_t)(rowb + r)*p.ldc + p.cofs + col;
        if(OUTBF) ((u16*)p.C)[idx] = f2b(v);
        else      ((float*)p.C)[idx] = v;
      }
    }
  }
}

// ====== fused QKV-projection + attention: block per (b, head, branch) =======
// All 4 K-tiles of A and B staged up-front (one vmcnt drain); 3 barriers total
// vs 11 in the per-tile version. LDS 62.5 KB, 2 blocks/CU (125 KB <= 160 KB).
struct QAArgs { const u16 *wq, *wk, *wv; const float *bq, *bk, *bv; };

__global__ __launch_bounds__(256, 2) void qkv_attn_kernel(
    const u16* __restrict__ h_bf,
    QAArgs a1, QAArgs a2,
    const u16* __restrict__ adjm16, const u16* __restrict__ distr16,
    const float* __restrict__ maskb,
    u16* __restrict__ o1, u16* __restrict__ o2)
{
  __shared__ u16 SH[32000];          // 62.5 KB
  u16* As4 = SH;                     // [4][128][32] = 16384 u16
  u16* Bs4 = SH + 16384;             // [4][96][32]  = 12288 u16 (q:0-31,k:32-63,v:64-95)
  u16* Ps  = SH;                     // [128][136]   = 17408 u16 (phase2, aliases staging)
  u16* Qs  = SH + 17408;             // [128][40]
  u16* Ks  = SH + 22528;             // [128][40]
  u16* Vt  = SH + 27648;             // [32][136]

  const int bh = blockIdx.x;
  const int b  = bh >> 2;
  const int hh = bh & 3;
  const int branch = blockIdx.y;
  const QAArgs qa = branch ? a2 : a1;
  const u16* wqp = qa.wq + (size_t)hh*32*DH_;
  const u16* wkp = qa.wk + (size_t)hh*32*DH_;
  const u16* wvp = qa.wv + (size_t)hh*32*DH_;
  const int t = threadIdx.x;
  const int w = t >> 6, lane = t & 63;
  const int ln = lane & 15, qd = lane >> 4;
  const size_t rowbase = (size_t)b * S_;
  const int srow = t >> 2, sc8 = (t & 3) * 8;
  const int mbase = w * 32;

  // ---- prefetch score-fixup operands (bf16) + mask (hidden behind MFMAs) ----
  u16 fixu[2][4][8];
  {
    const u16* basep = (branch ? distr16 : adjm16) + rowbase*S_;
    #pragma unroll
    for(int mt = 0; mt < 2; mt++)
      #pragma unroll
      for(int r = 0; r < 4; r++){
        int row = mbase + mt*16 + qd*4 + r;
        #pragma unroll
        for(int nt = 0; nt < 8; nt++)
          fixu[mt][r][nt] = basep[(size_t)row*S_ + nt*16 + ln];
      }
  }
  float mskv[8];
  if(branch){
    #pragma unroll
    for(int nt = 0; nt < 8; nt++) mskv[nt] = maskb[rowbase + nt*16 + ln];
  }

  // ---- stage ALL of A (128x128) and B (96x128) in one burst ----
  #pragma unroll
  for(int kc = 0; kc < 4; kc++){
    glds16(h_bf + (rowbase + srow)*D_ + branch*DH_ + kc*32 + sc8,
           As4 + kc*4096 + t*8);
    glds16(h_bf + (rowbase + 64 + srow)*D_ + branch*DH_ + kc*32 + sc8,
           As4 + kc*4096 + (t+256)*8);
    {
      int r = t >> 2;
      const u16* wp = (r < 32) ? wqp : wkp;
      glds16(wp + (size_t)(r & 31)*DH_ + kc*32 + sc8, Bs4 + kc*3072 + t*8);
    }
    if(t < 128){
      int c = 256 + t;
      glds16(wvp + (size_t)((c>>2) - 64)*DH_ + kc*32 + (c&3)*8, Bs4 + kc*3072 + c*8);
    }
  }
  __syncthreads();   // single drain for all 14 glds16/thread

  // ---- phase 1: QKV projection, barrier-free K-loop ----
  f32x4 acc[2][6];
  #pragma unroll
  for(int i=0;i<2;i++)
    #pragma unroll
    for(int j=0;j<6;j++) acc[i][j] = (f32x4){0.f,0.f,0.f,0.f};

  #pragma unroll
  for(int kc = 0; kc < 4; kc++){
    short8 av[2];
    #pragma unroll
    for(int mt = 0; mt < 2; mt++)
      av[mt] = *(const short8*)&As4[kc*4096 + (w*32 + mt*16 + ln)*32 + qd*8];
    #pragma unroll
    for(int nt = 0; nt < 6; nt++){
      short8 bv = *(const short8*)&Bs4[kc*3072 + (nt*16 + ln)*32 + qd*8];
      #pragma unroll
      for(int mt = 0; mt < 2; mt++)
        acc[mt][nt] = __builtin_amdgcn_mfma_f32_16x16x32_bf16(av[mt], bv, acc[mt][nt], 0, 0, 0);
    }
  }
  __syncthreads();   // staging region about to be overwritten by Qs/Ks/Vt

  // ---- epilogue: bias + scatter to Qs/Ks (row-major) and Vt (transposed) ----
  {
    const float* bqp = qa.bq + hh*32;
    const float* bkp = qa.bk + hh*32;
    const float* bvp = qa.bv + hh*32;
    #pragma unroll
    for(int mt = 0; mt < 2; mt++){
      int rb = w*32 + mt*16 + qd*4;
      #pragma unroll
      for(int j = 0; j < 2; j++){
        int d = j*16 + ln;
        float bq_ = bqp[d], bk_ = bkp[d], bv_ = bvp[d];
        #pragma unroll
        for(int r = 0; r < 4; r++){
          Qs[(rb+r)*40 + d]   = f2b(acc[mt][j][r]   + bq_);
          Ks[(rb+r)*40 + d]   = f2b(acc[mt][2+j][r] + bk_);
          Vt[d*136 + rb + r]  = f2b(acc[mt][4+j][r] + bv_);
        }
      }
    }
  }
  __syncthreads();

  // ---- phase 2: attention ----
  short8 qf[2];
  #pragma unroll
  for(int mt = 0; mt < 2; mt++)
    qf[mt] = *(const short8*)&Qs[(mbase + mt*16 + ln)*40 + qd*8];
  short8 kf[8];
  #pragma unroll
  for(int nt = 0; nt < 8; nt++)
    kf[nt] = *(const short8*)&Ks[(nt*16 + ln)*40 + qd*8];
  // no barrier: Ps (0..17407) is disjoint from Qs/Ks/Vt (17408..31999)

  f32x4 sc[2][8];
  #pragma unroll
  for(int mt = 0; mt < 2; mt++)
    #pragma unroll
    for(int nt = 0; nt < 8; nt++)
      sc[mt][nt] = __builtin_amdgcn_mfma_f32_16x16x32_bf16(
          qf[mt], kf[nt], (f32x4){0.f,0.f,0.f,0.f}, 0, 0, 0);

  #pragma unroll
  for(int mt = 0; mt < 2; mt++){
    #pragma unroll
    for(int r = 0; r < 4; r++){
      #pragma unroll
      for(int nt = 0; nt < 8; nt++){
        float g = b2f(fixu[mt][r][nt]);
        float v;
        if(branch == 0) v = sc[mt][nt][r]*SCALE_ + g;   // adjm has mask folded
        else            v = fmaxf(sc[mt][nt][r], 0.f)*g + mskv[nt];
        sc[mt][nt][r] = v;
      }
    }
  }

  #pragma unroll
  for(int mt = 0; mt < 2; mt++){
    #pragma unroll
    for(int r = 0; r < 4; r++){
      float m = -3.4e38f;
      #pragma unroll
      for(int nt = 0; nt < 8; nt++) m = fmaxf(m, sc[mt][nt][r]);
      m = fmaxf(m, __shfl_xor(m, 1));
      m = fmaxf(m, __shfl_xor(m, 2));
      m = fmaxf(m, __shfl_xor(m, 4));
      m = fmaxf(m, __shfl_xor(m, 8));
      float sum = 0.f;
      float e[8];
      #pragma unroll
      for(int nt = 0; nt < 8; nt++){ e[nt] = __expf(sc[mt][nt][r] - m); sum += e[nt]; }
      sum += __shfl_xor(sum, 1);
      sum += __shfl_xor(sum, 2);
      sum += __shfl_xor(sum, 4);
      sum += __shfl_xor(sum, 8);
      float inv = 1.0f / sum;
      int row = mbase + mt*16 + qd*4 + r;
      #pragma unroll
      for(int nt = 0; nt < 8; nt++) Ps[row*136 + nt*16 + ln] = f2b(e[nt] * inv);
    }
  }
  // no barrier: each wave reads only its own P rows

  f32x4 oacc[2][2];
  #pragma unroll
  for(int mt = 0; mt < 2; mt++)
    #pragma unroll
    for(int n2 = 0; n2 < 2; n2++) oacc[mt][n2] = (f32x4){0.f,0.f,0.f,0.f};
  #pragma unroll
  for(int kk = 0; kk < 4; kk++){
    short8 pa[2], vb[2];
    #pragma unroll
    for(int mt = 0; mt < 2; mt++)
      pa[mt] = *(const short8*)&Ps[(mbase + mt*16 + ln)*136 + kk*32 + qd*8];
    #pragma unroll
    for(int n2 = 0; n2 < 2; n2++)
      vb[n2] = *(const short8*)&Vt[(n2*16 + ln)*136 + kk*32 + qd*8];
    #pragma unroll
    for(int mt = 0; mt < 2; mt++)
      #pragma unroll
      for(int n2 = 0; n2 < 2; n2++)
        oacc[mt][n2] = __builtin_amdgcn_mfma_f32_16x16x32_bf16(pa[mt], vb[n2], oacc[mt][n2], 0, 0, 0);
  }

  u16* Og = branch ? o2 : o1;
  #pragma unroll
  for(int mt = 0; mt < 2; mt++){
    #pragma unroll
    for(int n2 = 0; n2 < 2; n2++){
      #pragma unroll
      for(int r = 0; r < 4; r++){
        int row = mbase + mt*16 + qd*4 + r;
        int d   = n2*16 + ln;
        Og[(rowbase + row)*DH_ + hh*DEPTH_ + d] = f2b(oacc[mt][n2][r]);
      }
    }
  }
}

// ====== fused layer tail: oproj(both)+res+LN1 + FFN1+GELU + FFN2+res+LN2 ====
// 512 thr (8 waves = 2/SIMD), 32 rows/block, grid 256.
struct TailArgs {
  const u16 *o1, *o2, *wo1, *wo2, *w1, *w2;
  const float *bo1, *bo2, *bf1, *bf2, *g1, *be1, *g2, *be2;
  float *h; u16 *h_bf;
};

__global__ __launch_bounds__(512) void tail_kernel(TailArgs p){
  __shared__ u16 X1[32*264];          // LN1 out bf16 [32][256+8pad]
  __shared__ u16 X2[32*520];          // gelu(ffn1) bf16 [32][512+8pad]
  __shared__ float redS[8][32], redQ[8][32];
  const int t = threadIdx.x;          // 0..511
  const int w = t >> 6, lane = t & 63;
  const int ln = lane & 15, qd = lane >> 4;
  const int m0 = blockIdx.x * 32;
  const int branch = w >> 2;          // waves 0-3: branch0, 4-7: branch1
  const int c0 = w * 32;              // global col base (oproj out & ffn2 out)
  const int bc0 = (w & 3) * 32;       // col base within branch

  // ---------------- phase A: out-projection ----------------
  const u16* Ao = branch ? p.o2 : p.o1;
  const u16* Wo = branch ? p.wo2 : p.wo1;
  const float* bo = branch ? p.bo2 : p.bo1;
  f32x4 y[2][2];
  #pragma unroll
  for(int mt=0;mt<2;mt++)
    #pragma unroll
    for(int nt=0;nt<2;nt++) y[mt][nt] = (f32x4){0.f,0.f,0.f,0.f};

  #pragma unroll
  for(int k0 = 0; k0 < DH_; k0 += 32){
    short8 af[2], bf[2];
    #pragma unroll
    for(int mt=0;mt<2;mt++)
      af[mt] = *(const short8*)(Ao + (size_t)(m0+mt*16+ln)*DH_ + k0 + qd*8);
    #pragma unroll
    for(int nt=0;nt<2;nt++)
      bf[nt] = *(const short8*)(Wo + (size_t)(bc0+nt*16+ln)*DH_ + k0 + qd*8);
    #pragma unroll
    for(int mt=0;mt<2;mt++)
      #pragma unroll
      for(int nt=0;nt<2;nt++)
        y[mt][nt] = __builtin_amdgcn_mfma_f32_16x16x32_bf16(af[mt], bf[nt], y[mt][nt], 0, 0, 0);
  }

  float sS[2][4] = {}, sQ[2][4] = {};
  #pragma unroll
  for(int mt=0;mt<2;mt++){
    #pragma unroll
    for(int nt=0;nt<2;nt++){
      int col = c0 + nt*16 + ln;
      float bv = bo[bc0 + nt*16 + ln];
      #pragma unroll
      for(int r=0;r<4;r++){
        float v = y[mt][nt][r] + bv + p.h[(size_t)(m0+mt*16+qd*4+r)*D_ + col];
        y[mt][nt][r] = v;
        sS[mt][r] += v;
        sQ[mt][r] += v*v;
      }
    }
  }
  #pragma unroll
  for(int mt=0;mt<2;mt++)
    #pragma unroll
    for(int r=0;r<4;r++){
      float a = sS[mt][r], b = sQ[mt][r];
      a += __shfl_xor(a,1); a += __shfl_xor(a,2); a += __shfl_xor(a,4); a += __shfl_xor(a,8);
      b += __shfl_xor(b,1); b += __shfl_xor(b,2); b += __shfl_xor(b,4); b += __shfl_xor(b,8);
      sS[mt][r] = a; sQ[mt][r] = b;
    }
  if(ln == 0){
    #pragma unroll
    for(int mt=0;mt<2;mt++)
      #pragma unroll
      for(int r=0;r<4;r++){
        int row = mt*16 + qd*4 + r;
        redS[w][row] = sS[mt][r];
        redQ[w][row] = sQ[mt][r];
      }
  }
  __syncthreads();
  float mu[2][4], iv[2][4];
  #pragma unroll
  for(int mt=0;mt<2;mt++)
    #pragma unroll
    for(int r=0;r<4;r++){
      int row = mt*16 + qd*4 + r;
      float s = 0.f, q = 0.f;
      #pragma unroll
      for(int ww=0;ww<8;ww++){ s += redS[ww][row]; q += redQ[ww][row]; }
      float m_ = s * (1.0f/D_);
      mu[mt][r] = m_;
      iv[mt][r] = rsqrtf(q*(1.0f/D_) - m_*m_ + 1e-6f);
    }
  #pragma unroll
  for(int mt=0;mt<2;mt++){
    #pragma unroll
    for(int nt=0;nt<2;nt++){
      int col = c0 + nt*16 + ln;
      float gg = p.g1[col], bb = p.be1[col];
      #pragma unroll
      for(int r=0;r<4;r++){
        float yy = (y[mt][nt][r] - mu[mt][r]) * iv[mt][r] * gg + bb;
        y[mt][nt][r] = yy;
        X1[(mt*16+qd*4+r)*264 + col] = f2b(yy);
      }
    }
  }
  __syncthreads();

  // ---------------- phase B: FFN1 + GELU (wave owns 64 cols) ----------------
  {
    const int fc0 = w * 64;
    f32x4 f1[2][4];
    #pragma unroll
    for(int mt=0;mt<2;mt++)
      #pragma unroll
      for(int nt=0;nt<4;nt++) f1[mt][nt] = (f32x4){0.f,0.f,0.f,0.f};
    for(int k0 = 0; k0 < D_; k0 += 32){
      short8 a0 = *(const short8*)&X1[(ln)*264 + k0 + qd*8];
      short8 a1 = *(const short8*)&X1[(16+ln)*264 + k0 + qd*8];
      #pragma unroll
      for(int nt=0;nt<4;nt++){
        short8 bfr = *(const short8*)(p.w1 + (size_t)(fc0+nt*16+ln)*D_ + k0 + qd*8);
        f1[0][nt] = __builtin_amdgcn_mfma_f32_16x16x32_bf16(a0, bfr, f1[0][nt], 0, 0, 0);
        f1[1][nt] = __builtin_amdgcn_mfma_f32_16x16x32_bf16(a1, bfr, f1[1][nt], 0, 0, 0);
      }
    }
    #pragma unroll
    for(int mt=0;mt<2;mt++){
      #pragma unroll
      for(int nt=0;nt<4;nt++){
        int col = fc0 + nt*16 + ln;
        float bv = p.bf1[col];
        #pragma unroll
        for(int r=0;r<4;r++){
          float v = f1[mt][nt][r] + bv;
          v = 0.5f*v*(1.0f + erff(v*0.70710678118654752f));
          X2[(mt*16+qd*4+r)*520 + col] = f2b(v);
        }
      }
    }
  }
  __syncthreads();

  // ---------------- phase C: FFN2 + residual + LN2 (wave owns 32 cols) ------
  f32x4 f2[2][2];
  #pragma unroll
  for(int mt=0;mt<2;mt++)
    #pragma unroll
    for(int nt=0;nt<2;nt++) f2[mt][nt] = (f32x4){0.f,0.f,0.f,0.f};
  for(int k0 = 0; k0 < DFF_; k0 += 32){
    short8 a0 = *(const short8*)&X2[(ln)*520 + k0 + qd*8];
    short8 a1 = *(const short8*)&X2[(16+ln)*520 + k0 + qd*8];
    #pragma unroll
    for(int nt=0;nt<2;nt++){
      short8 bfr = *(const short8*)(p.w2 + (size_t)(c0+nt*16+ln)*DFF_ + k0 + qd*8);
      f2[0][nt] = __builtin_amdgcn_mfma_f32_16x16x32_bf16(a0, bfr, f2[0][nt], 0, 0, 0);
      f2[1][nt] = __builtin_amdgcn_mfma_f32_16x16x32_bf16(a1, bfr, f2[1][nt], 0, 0, 0);
    }
  }
  float sS2[2][4] = {}, sQ2[2][4] = {};
  #pragma unroll
  for(int mt=0;mt<2;mt++){
    #pragma unroll
    for(int nt=0;nt<2;nt++){
      int col = c0 + nt*16 + ln;
      float bv = p.bf2[col];
      #pragma unroll
      for(int r=0;r<4;r++){
        float v = f2[mt][nt][r] + bv + y[mt][nt][r];   // residual = LN1 out (regs)
        f2[mt][nt][r] = v;
        sS2[mt][r] += v;
        sQ2[mt][r] += v*v;
      }
    }
  }
  #pragma unroll
  for(int mt=0;mt<2;mt++)
    #pragma unroll
    for(int r=0;r<4;r++){
      float a = sS2[mt][r], b = sQ2[mt][r];
      a += __shfl_xor(a,1); a += __shfl_xor(a,2); a += __shfl_xor(a,4); a += __shfl_xor(a,8);
      b += __shfl_xor(b,1); b += __shfl_xor(b,2); b += __shfl_xor(b,4); b += __shfl_xor(b,8);
      sS2[mt][r] = a; sQ2[mt][r] = b;
    }
  if(ln == 0){
    #pragma unroll
    for(int mt=0;mt<2;mt++)
      #pragma unroll
      for(int r=0;r<4;r++){
        int row = mt*16 + qd*4 + r;
        redS[w][row] = sS2[mt][r];
        redQ[w][row] = sQ2[mt][r];
      }
  }
  __syncthreads();
  #pragma unroll
  for(int mt=0;mt<2;mt++)
    #pragma unroll
    for(int r=0;r<4;r++){
      int row = mt*16 + qd*4 + r;
      float s = 0.f, q = 0.f;
      #pragma unroll
      for(int ww=0;ww<8;ww++){ s += redS[ww][row]; q += redQ[ww][row]; }
      float m_ = s * (1.0f/D_);
      mu[mt][r] = m_;
      iv[mt][r] = rsqrtf(q*(1.0f/D_) - m_*m_ + 1e-6f);
    }
  #pragma unroll
  for(int mt=0;mt<2;mt++){
    #pragma unroll
    for(int nt=0;nt<2;nt++){
      int col = c0 + nt*16 + ln;
      float gg = p.g2[col], bb = p.be2[col];
      #pragma unroll
      for(int r=0;r<4;r++){
        float yy = (f2[mt][nt][r] - mu[mt][r]) * iv[mt][r] * gg + bb;
        size_t idx = (size_t)(m0 + mt*16 + qd*4 + r)*D_ + col;
        p.h[idx] = yy;
        p.h_bf[idx] = f2b(yy);
      }
    }
  }
}

// ---------------- pooled[b,n,:] = (amm[b,n,:] @ h[b]) / sum_atoms -----------
__global__ __launch_bounds__(256) void pool_kernel(
    const float* __restrict__ amm, const float* __restrict__ sum_atoms,
    const float* __restrict__ h, u16* __restrict__ pooled_bf)
{
  __shared__ float as[S_];
  int bn = blockIdx.x;
  int b  = bn >> 5;
  int t  = threadIdx.x;
  if(t < S_) as[t] = amm[(size_t)bn*S_ + t];
  __syncthreads();
  float acc = 0.f;
  const float* hb = h + (size_t)b*S_*D_ + t;
  #pragma unroll 4
  for(int s = 0; s < S_; s++) acc = fmaf(as[s], hb[(size_t)s*D_], acc);
  pooled_bf[(size_t)bn*D_ + t] = f2b(acc / sum_atoms[bn]);
}

// ============================ host-side launcher ============================
extern "C" void kernel_launch(void* const* d_in, const int* in_sizes, int n_in,
                              void* d_out, int out_size, void* d_ws, size_t ws_size,
                              hipStream_t stream)
{
  const float* x     = (const float*)d_in[0];
  const float* adj   = (const float*)d_in[1];
  const float* dist  = (const float*)d_in[2];
  const float* amm   = (const float*)d_in[3];
  const float* sum_a = (const float*)d_in[4];
  const float* embW  = (const float*)d_in[5];
  const float* embB  = (const float*)d_in[6];
  const float* globW = (const float*)d_in[7];
  const float* globB = (const float*)d_in[8];
  const float* Wq1 = (const float*)d_in[9],  *Wk1 = (const float*)d_in[10],
             *Wv1 = (const float*)d_in[11], *Wo1 = (const float*)d_in[12],
             *Wq2 = (const float*)d_in[13], *Wk2 = (const float*)d_in[14],
             *Wv2 = (const float*)d_in[15], *Wo2 = (const float*)d_in[16];
  const float* bq1 = (const float*)d_in[17], *bk1 = (const float*)d_in[18],
             *bv1 = (const float*)d_in[19], *bo1 = (const float*)d_in[20],
             *bq2 = (const float*)d_in[21], *bk2 = (const float*)d_in[22],
             *bv2 = (const float*)d_in[23], *bo2 = (const float*)d_in[24];
  const float* Wf1 = (const float*)d_in[25], *bf1 = (const float*)d_in[26],
             *Wf2 = (const float*)d_in[27], *bf2 = (const float*)d_in[28],
             *g1  = (const float*)d_in[29], *be1 = (const float*)d_in[30],
             *g2  = (const float*)d_in[31], *be2 = (const float*)d_in[32];

  float* wsf = (float*)d_ws;
  float* h     = wsf; wsf += (size_t)MS_*D_;
  float* maskb = wsf; wsf += MS_;
  // bf16 region
  u16* bb = (u16*)wsf;
  u16* adjm16  = bb; bb += (size_t)B_*S_*S_;
  u16* distr16 = bb; bb += (size_t)B_*S_*S_;
  u16* o1_bf   = bb; bb += (size_t)MS_*DH_;
  u16* o2_bf   = bb; bb += (size_t)MS_*DH_;
  u16* h_bf    = bb; bb += (size_t)MS_*D_;
  u16* pooled_bf = bb; bb += (size_t)B_*NSUB_*D_;
  u16* globWt  = bb; bb += (size_t)D_*D_;
  u16* wq1t = bb; bb += (size_t)L_*DH_*DH_;
  u16* wk1t = bb; bb += (size_t)L_*DH_*DH_;
  u16* wv1t = bb; bb += (size_t)L_*DH_*DH_;
  u16* wo1t = bb; bb += (size_t)L_*DH_*DH_;
  u16* wq2t = bb; bb += (size_t)L_*DH_*DH_;
  u16* wk2t = bb; bb += (size_t)L_*DH_*DH_;
  u16* wv2t = bb; bb += (size_t)L_*DH_*DH_;
  u16* wo2t = bb; bb += (size_t)L_*DH_*DH_;
  u16* wf1t = bb; bb += (size_t)L_*D_*DFF_;       // [L][512][256]
  u16* wf2t = bb; bb += (size_t)L_*DFF_*D_;       // [L][256][512]

  embed_kernel<<<MS_/4, 256, 0, stream>>>(x, embW, embB, h, h_bf, maskb);
  adjrescale_kernel<<<(B_*S_*S_)/256, 256, 0, stream>>>(adj, dist, maskb, adjm16, distr16);
  {
    TDs td;
    const float* S8[8] = {Wq1, Wk1, Wv1, Wo1, Wq2, Wk2, Wv2, Wo2};
    u16* D8[8] = {wq1t, wk1t, wv1t, wo1t, wq2t, wk2t, wv2t, wo2t};
    for(int i = 0; i < 8; i++) td.d[i] = {S8[i], D8[i], DH_, DH_, L_};
    td.d[8]  = {Wf1, wf1t, D_, DFF_, L_};
    td.d[9]  = {Wf2, wf2t, DFF_, D_, L_};
    td.d[10] = {globW, globWt, D_, D_, 1};
    transpose_all_kernel<<<dim3(16,16,11), dim3(32,8), 0, stream>>>(td);
  }

  for(int l = 0; l < L_; l++){
    QAArgs a1 = { wq1t + (size_t)l*DH_*DH_, wk1t + (size_t)l*DH_*DH_, wv1t + (size_t)l*DH_*DH_,
                  bq1 + (size_t)l*DH_, bk1 + (size_t)l*DH_, bv1 + (size_t)l*DH_ };
    QAArgs a2 = { wq2t + (size_t)l*DH_*DH_, wk2t + (size_t)l*DH_*DH_, wv2t + (size_t)l*DH_*DH_,
                  bq2 + (size_t)l*DH_, bk2 + (size_t)l*DH_, bv2 + (size_t)l*DH_ };
    qkv_attn_kernel<<<dim3(B_*H_, 2), 256, 0, stream>>>(h_bf, a1, a2, adjm16, distr16, maskb,
                                                        o1_bf, o2_bf);
    TailArgs ta;
    ta.o1 = o1_bf; ta.o2 = o2_bf;
    ta.wo1 = wo1t + (size_t)l*DH_*DH_; ta.wo2 = wo2t + (size_t)l*DH_*DH_;
    ta.w1 = wf1t + (size_t)l*D_*DFF_;  ta.w2 = wf2t + (size_t)l*DFF_*D_;
    ta.bo1 = bo1 + (size_t)l*DH_; ta.bo2 = bo2 + (size_t)l*DH_;
    ta.bf1 = bf1 + (size_t)l*DFF_; ta.bf2 = bf2 + (size_t)l*D_;
    ta.g1 = g1 + (size_t)l*D_; ta.be1 = be1 + (size_t)l*D_;
    ta.g2 = g2 + (size_t)l*D_; ta.be2 = be2 + (size_t)l*D_;
    ta.h = h; ta.h_bf = h_bf;
    tail_kernel<<<MS_/32, 512, 0, stream>>>(ta);
  }

  pool_kernel<<<B_*NSUB_, 256, 0, stream>>>(amm, sum_a, h, pooled_bf);
  // final: relu(pooled @ glob_W + glob_b), M=2048 N=256 K=256
  {
    MG6 a;
    a.g[0].A = pooled_bf; a.g[0].W = globWt;
    a.g[0].bias = globB; a.g[0].C = (float*)d_out;
    a.g[0].lda = D_; a.g[0].K = D_; a.g[0].ldc = D_;
    a.g[0].aofs = 0; a.g[0].cofs = 0;
    mgemm_kernel<64,false,1><<<dim3((B_*NSUB_)/64, D_/128, 1), 256, 0, stream>>>(a);
  }
}

// Round 12
// 428.052 us; speedup vs baseline: 3.6479x; 1.0149x over previous
//
#include <hip/hip_runtime.h>
#include <math.h>

#define B_ 64
#define S_ 128
#define F_ 62
#define D_ 256
#define H_ 4
#define L_ 6
#define NSUB_ 32
#define DFF_ 512
#define DH_ 128
#define DEPTH_ 32
#define MS_ (B_*S_)                 // 8192 rows
#define NEGV (-1000000000.0f)
#define SCALE_ 0.17677669529663687f // 1/sqrt(32)

typedef unsigned short u16;
typedef __attribute__((ext_vector_type(8))) short short8;
typedef __attribute__((ext_vector_type(4))) float f32x4;

// f32 -> bf16 round-to-nearest-even
__device__ __forceinline__ u16 f2b(float f){
  unsigned u = __float_as_uint(f);
  unsigned r = (u + 0x7fffu + ((u >> 16) & 1u)) >> 16;
  return (u16)r;
}
__device__ __forceinline__ float b2f(u16 v){
  return __uint_as_float((unsigned)v << 16);
}

__device__ __forceinline__ void glds16(const void* g, void* l){
  __builtin_amdgcn_global_load_lds(
      (const __attribute__((address_space(1))) unsigned int*)g,
      (__attribute__((address_space(3))) unsigned int*)l, 16, 0, 0);
}

// ------- adjm16 = bf16(adj + mask); distr16 = bf16(rescale(dist)*scale) -----
__global__ __launch_bounds__(256) void adjrescale_kernel(
    const float* __restrict__ adj, const float* __restrict__ dist,
    const float* __restrict__ maskb,
    u16* __restrict__ adjm16, u16* __restrict__ distr16){
  size_t i = (size_t)blockIdx.x*256 + threadIdx.x;
  int j = (int)(i & (S_-1));
  int b = (int)(i >> 14);            // S_*S_ = 16384
  const float e1 = 2.718281828459045f;
  distr16[i] = f2b((1.0f + e1) / (1.0f + expf(1.0f - dist[i])) * SCALE_);
  adjm16[i]  = f2b(adj[i] + maskb[b*S_ + j]);
}

// ------ all weight transposes in ONE dispatch: dst[l][n][k] = src[l][k][n] --
struct TD { const float* src; u16* dst; int K, N, L; };
struct TDs { TD d[11]; };
__global__ __launch_bounds__(256) void transpose_all_kernel(TDs a){
  const TD p = a.d[blockIdx.z];
  int n0 = blockIdx.x*32, k0 = blockIdx.y*32;
  if(n0 >= p.N || k0 >= p.K) return;
  __shared__ float tbuf[32][33];
  int tx = threadIdx.x, ty = threadIdx.y;   // 32 x 8
  for(int l = 0; l < p.L; l++){
    const float* src = p.src + (size_t)l*p.K*p.N;
    u16* dst = p.dst + (size_t)l*p.K*p.N;
    #pragma unroll
    for(int i = 0; i < 4; i++)
      tbuf[ty + i*8][tx] = src[(size_t)(k0 + ty + i*8)*p.N + n0 + tx];
    __syncthreads();
    #pragma unroll
    for(int i = 0; i < 4; i++)
      dst[(size_t)(n0 + ty + i*8)*p.K + k0 + tx] = f2b(tbuf[tx][ty + i*8]);
    __syncthreads();
  }
}

// --------- embed: h = relu(x @ emb_W + emb_b), K=62; also emits maskb -------
__global__ __launch_bounds__(256) void embed_kernel(const float* __restrict__ x,
    const float* __restrict__ W, const float* __restrict__ bias,
    float* __restrict__ h, u16* __restrict__ h_bf, float* __restrict__ maskb){
  __shared__ float xs[4][F_];
  int r0 = blockIdx.x*4;
  int t = threadIdx.x;
  if(t < 4*F_){ int rr = t / F_, ff = t - rr*F_; xs[rr][ff] = x[(size_t)(r0+rr)*F_ + ff]; }
  __syncthreads();
  if(t < 4){
    float s = 0.f;
    #pragma unroll
    for(int f = 0; f < F_; f++) s += xs[t][f];
    maskb[r0 + t] = (s == 0.0f) ? NEGV : 0.0f;
  }
  float b = bias[t];
  float a0=b, a1=b, a2=b, a3=b;
  for(int k=0; k<F_; k++){
    float w = W[k*D_ + t];
    a0 = fmaf(xs[0][k], w, a0);
    a1 = fmaf(xs[1][k], w, a1);
    a2 = fmaf(xs[2][k], w, a2);
    a3 = fmaf(xs[3][k], w, a3);
  }
  a0 = fmaxf(a0, 0.f); a1 = fmaxf(a1, 0.f); a2 = fmaxf(a2, 0.f); a3 = fmaxf(a3, 0.f);
  h[(size_t)(r0+0)*D_ + t] = a0;  h_bf[(size_t)(r0+0)*D_ + t] = f2b(a0);
  h[(size_t)(r0+1)*D_ + t] = a1;  h_bf[(size_t)(r0+1)*D_ + t] = f2b(a1);
  h[(size_t)(r0+2)*D_ + t] = a2;  h_bf[(size_t)(r0+2)*D_ + t] = f2b(a2);
  h[(size_t)(r0+3)*D_ + t] = a3;  h_bf[(size_t)(r0+3)*D_ + t] = f2b(a3);
}

// =================== bf16 MFMA GEMM (final GEMM only) =======================
struct MG {
  const u16* A; const u16* W; const float* bias; void* C;
  int lda, K, ldc, aofs, cofs;
};
struct MG6 { MG g[6]; };

template<int TM, bool OUTBF, int ACT>
__global__ __launch_bounds__(256) void mgemm_kernel(MG6 args){
  const MG p = args.g[blockIdx.z];
  __shared__ u16 As[TM*32];
  __shared__ u16 Bs[128*32];
  const int t    = threadIdx.x;
  const int lane = t & 63;
  const int w    = t >> 6;
  const int ln   = lane & 15;
  const int qd   = lane >> 4;
  const int mw   = (w & 1) * (TM/2);
  const int nw   = (w >> 1) * 64;
  const int m0   = blockIdx.x * TM;
  const int n0   = blockIdx.y * 128;
  constexpr int MI = TM/32;
  f32x4 acc[MI][4];
  #pragma unroll
  for(int i=0;i<MI;i++)
    #pragma unroll
    for(int j=0;j<4;j++) acc[i][j] = (f32x4){0.f,0.f,0.f,0.f};

  const int srow = t >> 2;
  const int sc8  = (t & 3) * 8;

  for(int k0 = 0; k0 < p.K; k0 += 32){
    __syncthreads();
    glds16(p.A + (size_t)(m0 + srow)*p.lda + p.aofs + k0 + sc8, As + t*8);
    if(TM == 128)
      glds16(p.A + (size_t)(m0 + 64 + srow)*p.lda + p.aofs + k0 + sc8, As + (t+256)*8);
    glds16(p.W + (size_t)(n0 + srow)*p.K + k0 + sc8, Bs + t*8);
    glds16(p.W + (size_t)(n0 + 64 + srow)*p.K + k0 + sc8, Bs + (t+256)*8);
    __syncthreads();

    short8 a[MI], b[4];
    #pragma unroll
    for(int i=0;i<MI;i++) a[i] = *(const short8*)&As[(mw + i*16 + ln)*32 + qd*8];
    #pragma unroll
    for(int j=0;j<4;j++)  b[j] = *(const short8*)&Bs[(nw + j*16 + ln)*32 + qd*8];
    #pragma unroll
    for(int i=0;i<MI;i++)
      #pragma unroll
      for(int j=0;j<4;j++)
        acc[i][j] = __builtin_amdgcn_mfma_f32_16x16x32_bf16(a[i], b[j], acc[i][j], 0, 0, 0);
  }

  #pragma unroll
  for(int i=0;i<MI;i++){
    #pragma unroll
    for(int j=0;j<4;j++){
      int col = n0 + nw + j*16 + ln;
      float bv = p.bias[col];
      int rowb = m0 + mw + i*16 + qd*4;
      #pragma unroll
      for(int r=0;r<4;r++){
        float v = acc[i][j][r] + bv;
        if(ACT == 1) v = fmaxf(v, 0.f);
        if(ACT == 2) v = 0.5f*v*(1.0f + erff(v*0.70710678118654752f));
        size_t idx = (size_t)(rowb + r)*p.ldc + p.cofs + col;
        if(OUTBF) ((u16*)p.C)[idx] = f2b(v);
        else      ((float*)p.C)[idx] = v;
      }
    }
  }
}

// ====== fused QKV-projection + attention: block per (b, head, branch) =======
// All 4 K-tiles staged up-front (single vmcnt drain), 3 barriers total.
struct QAArgs { const u16 *wq, *wk, *wv; const float *bq, *bk, *bv; };

__global__ __launch_bounds__(256, 2) void qkv_attn_kernel(
    const u16* __restrict__ h_bf,
    QAArgs a1, QAArgs a2,
    const u16* __restrict__ adjm16, const u16* __restrict__ distr16,
    const float* __restrict__ maskb,
    u16* __restrict__ o1, u16* __restrict__ o2)
{
  __shared__ u16 SH[32000];          // 62.5 KB
  u16* As4 = SH;                     // [4][128][32]
  u16* Bs4 = SH + 16384;             // [4][96][32]
  u16* Ps  = SH;                     // [128][136] (phase2, aliases staging)
  u16* Qs  = SH + 17408;             // [128][40]
  u16* Ks  = SH + 22528;             // [128][40]
  u16* Vt  = SH + 27648;             // [32][136]

  const int bh = blockIdx.x;
  const int b  = bh >> 2;
  const int hh = bh & 3;
  const int branch = blockIdx.y;
  const QAArgs qa = branch ? a2 : a1;
  const u16* wqp = qa.wq + (size_t)hh*32*DH_;
  const u16* wkp = qa.wk + (size_t)hh*32*DH_;
  const u16* wvp = qa.wv + (size_t)hh*32*DH_;
  const int t = threadIdx.x;
  const int w = t >> 6, lane = t & 63;
  const int ln = lane & 15, qd = lane >> 4;
  const size_t rowbase = (size_t)b * S_;
  const int srow = t >> 2, sc8 = (t & 3) * 8;
  const int mbase = w * 32;

  // ---- prefetch score-fixup operands (bf16) + mask (hidden behind MFMAs) ----
  u16 fixu[2][4][8];
  {
    const u16* basep = (branch ? distr16 : adjm16) + rowbase*S_;
    #pragma unroll
    for(int mt = 0; mt < 2; mt++)
      #pragma unroll
      for(int r = 0; r < 4; r++){
        int row = mbase + mt*16 + qd*4 + r;
        #pragma unroll
        for(int nt = 0; nt < 8; nt++)
          fixu[mt][r][nt] = basep[(size_t)row*S_ + nt*16 + ln];
      }
  }
  float mskv[8];
  if(branch){
    #pragma unroll
    for(int nt = 0; nt < 8; nt++) mskv[nt] = maskb[rowbase + nt*16 + ln];
  }

  // ---- stage ALL of A (128x128) and B (96x128) in one burst ----
  #pragma unroll
  for(int kc = 0; kc < 4; kc++){
    glds16(h_bf + (rowbase + srow)*D_ + branch*DH_ + kc*32 + sc8,
           As4 + kc*4096 + t*8);
    glds16(h_bf + (rowbase + 64 + srow)*D_ + branch*DH_ + kc*32 + sc8,
           As4 + kc*4096 + (t+256)*8);
    {
      int r = t >> 2;
      const u16* wp = (r < 32) ? wqp : wkp;
      glds16(wp + (size_t)(r & 31)*DH_ + kc*32 + sc8, Bs4 + kc*3072 + t*8);
    }
    if(t < 128){
      int c = 256 + t;
      glds16(wvp + (size_t)((c>>2) - 64)*DH_ + kc*32 + (c&3)*8, Bs4 + kc*3072 + c*8);
    }
  }
  __syncthreads();   // single drain for all 14 glds16/thread

  // ---- phase 1: QKV projection, barrier-free K-loop ----
  f32x4 acc[2][6];
  #pragma unroll
  for(int i=0;i<2;i++)
    #pragma unroll
    for(int j=0;j<6;j++) acc[i][j] = (f32x4){0.f,0.f,0.f,0.f};

  #pragma unroll
  for(int kc = 0; kc < 4; kc++){
    short8 av[2];
    #pragma unroll
    for(int mt = 0; mt < 2; mt++)
      av[mt] = *(const short8*)&As4[kc*4096 + (w*32 + mt*16 + ln)*32 + qd*8];
    #pragma unroll
    for(int nt = 0; nt < 6; nt++){
      short8 bv = *(const short8*)&Bs4[kc*3072 + (nt*16 + ln)*32 + qd*8];
      #pragma unroll
      for(int mt = 0; mt < 2; mt++)
        acc[mt][nt] = __builtin_amdgcn_mfma_f32_16x16x32_bf16(av[mt], bv, acc[mt][nt], 0, 0, 0);
    }
  }
  __syncthreads();   // staging region about to be overwritten by Qs/Ks/Vt

  // ---- epilogue: bias + scatter to Qs/Ks (row-major) and Vt (transposed) ----
  {
    const float* bqp = qa.bq + hh*32;
    const float* bkp = qa.bk + hh*32;
    const float* bvp = qa.bv + hh*32;
    #pragma unroll
    for(int mt = 0; mt < 2; mt++){
      int rb = w*32 + mt*16 + qd*4;
      #pragma unroll
      for(int j = 0; j < 2; j++){
        int d = j*16 + ln;
        float bq_ = bqp[d], bk_ = bkp[d], bv_ = bvp[d];
        #pragma unroll
        for(int r = 0; r < 4; r++){
          Qs[(rb+r)*40 + d]   = f2b(acc[mt][j][r]   + bq_);
          Ks[(rb+r)*40 + d]   = f2b(acc[mt][2+j][r] + bk_);
          Vt[d*136 + rb + r]  = f2b(acc[mt][4+j][r] + bv_);
        }
      }
    }
  }
  __syncthreads();

  // ---- phase 2: attention ----
  short8 qf[2];
  #pragma unroll
  for(int mt = 0; mt < 2; mt++)
    qf[mt] = *(const short8*)&Qs[(mbase + mt*16 + ln)*40 + qd*8];
  short8 kf[8];
  #pragma unroll
  for(int nt = 0; nt < 8; nt++)
    kf[nt] = *(const short8*)&Ks[(nt*16 + ln)*40 + qd*8];
  // no barrier: Ps (0..17407) disjoint from Qs/Ks/Vt (17408..31999)

  f32x4 sc[2][8];
  #pragma unroll
  for(int mt = 0; mt < 2; mt++)
    #pragma unroll
    for(int nt = 0; nt < 8; nt++)
      sc[mt][nt] = __builtin_amdgcn_mfma_f32_16x16x32_bf16(
          qf[mt], kf[nt], (f32x4){0.f,0.f,0.f,0.f}, 0, 0, 0);

  #pragma unroll
  for(int mt = 0; mt < 2; mt++){
    #pragma unroll
    for(int r = 0; r < 4; r++){
      #pragma unroll
      for(int nt = 0; nt < 8; nt++){
        float g = b2f(fixu[mt][r][nt]);
        float v;
        if(branch == 0) v = sc[mt][nt][r]*SCALE_ + g;   // adjm has mask folded
        else            v = fmaxf(sc[mt][nt][r], 0.f)*g + mskv[nt];
        sc[mt][nt][r] = v;
      }
    }
  }

  #pragma unroll
  for(int mt = 0; mt < 2; mt++){
    #pragma unroll
    for(int r = 0; r < 4; r++){
      float m = -3.4e38f;
      #pragma unroll
      for(int nt = 0; nt < 8; nt++) m = fmaxf(m, sc[mt][nt][r]);
      m = fmaxf(m, __shfl_xor(m, 1));
      m = fmaxf(m, __shfl_xor(m, 2));
      m = fmaxf(m, __shfl_xor(m, 4));
      m = fmaxf(m, __shfl_xor(m, 8));
      float sum = 0.f;
      float e[8];
      #pragma unroll
      for(int nt = 0; nt < 8; nt++){ e[nt] = __expf(sc[mt][nt][r] - m); sum += e[nt]; }
      sum += __shfl_xor(sum, 1);
      sum += __shfl_xor(sum, 2);
      sum += __shfl_xor(sum, 4);
      sum += __shfl_xor(sum, 8);
      float inv = 1.0f / sum;
      int row = mbase + mt*16 + qd*4 + r;
      #pragma unroll
      for(int nt = 0; nt < 8; nt++) Ps[row*136 + nt*16 + ln] = f2b(e[nt] * inv);
    }
  }
  // no barrier: each wave reads only its own P rows

  f32x4 oacc[2][2];
  #pragma unroll
  for(int mt = 0; mt < 2; mt++)
    #pragma unroll
    for(int n2 = 0; n2 < 2; n2++) oacc[mt][n2] = (f32x4){0.f,0.f,0.f,0.f};
  #pragma unroll
  for(int kk = 0; kk < 4; kk++){
    short8 pa[2], vb[2];
    #pragma unroll
    for(int mt = 0; mt < 2; mt++)
      pa[mt] = *(const short8*)&Ps[(mbase + mt*16 + ln)*136 + kk*32 + qd*8];
    #pragma unroll
    for(int n2 = 0; n2 < 2; n2++)
      vb[n2] = *(const short8*)&Vt[(n2*16 + ln)*136 + kk*32 + qd*8];
    #pragma unroll
    for(int mt = 0; mt < 2; mt++)
      #pragma unroll
      for(int n2 = 0; n2 < 2; n2++)
        oacc[mt][n2] = __builtin_amdgcn_mfma_f32_16x16x32_bf16(pa[mt], vb[n2], oacc[mt][n2], 0, 0, 0);
  }

  u16* Og = branch ? o2 : o1;
  #pragma unroll
  for(int mt = 0; mt < 2; mt++){
    #pragma unroll
    for(int n2 = 0; n2 < 2; n2++){
      #pragma unroll
      for(int r = 0; r < 4; r++){
        int row = mbase + mt*16 + qd*4 + r;
        int d   = n2*16 + ln;
        Og[(rowbase + row)*DH_ + hh*DEPTH_ + d] = f2b(oacc[mt][n2][r]);
      }
    }
  }
}

// ====== fused layer tail: oproj(both)+res+LN1 + FFN1+GELU + FFN2+res+LN2 ====
// 512 thr, 32 rows/block, grid 256. Register software-pipelining in all three
// K-loops to raise in-flight global loads (was compiler-limited at VGPR=76).
struct TailArgs {
  const u16 *o1, *o2, *wo1, *wo2, *w1, *w2;
  const float *bo1, *bo2, *bf1, *bf2, *g1, *be1, *g2, *be2;
  float *h; u16 *h_bf;
};

__global__ __launch_bounds__(512) void tail_kernel(TailArgs p){
  __shared__ u16 X1[32*264];          // LN1 out bf16 [32][256+8pad]
  __shared__ u16 X2[32*520];          // gelu(ffn1) bf16 [32][512+8pad]
  __shared__ float redS[8][32], redQ[8][32];
  const int t = threadIdx.x;          // 0..511
  const int w = t >> 6, lane = t & 63;
  const int ln = lane & 15, qd = lane >> 4;
  const int m0 = blockIdx.x * 32;
  const int branch = w >> 2;          // waves 0-3: branch0, 4-7: branch1
  const int c0 = w * 32;              // global col base (oproj out & ffn2 out)
  const int bc0 = (w & 3) * 32;       // col base within branch

  // ---------------- phase A: out-projection (all frags hoisted) -------------
  const u16* Ao = branch ? p.o2 : p.o1;
  const u16* Wo = branch ? p.wo2 : p.wo1;
  const float* bo = branch ? p.bo2 : p.bo1;

  // residual prefetch (independent of everything)
  float resv[2][2][4];
  #pragma unroll
  for(int mt=0;mt<2;mt++)
    #pragma unroll
    for(int nt=0;nt<2;nt++){
      int col = c0 + nt*16 + ln;
      #pragma unroll
      for(int r=0;r<4;r++)
        resv[mt][nt][r] = p.h[(size_t)(m0+mt*16+qd*4+r)*D_ + col];
    }

  // hoist all 8 A-frags and 8 B-frags
  short8 afr[4][2], bfr4[4][2];
  #pragma unroll
  for(int kc=0;kc<4;kc++){
    #pragma unroll
    for(int mt=0;mt<2;mt++)
      afr[kc][mt] = *(const short8*)(Ao + (size_t)(m0+mt*16+ln)*DH_ + kc*32 + qd*8);
    #pragma unroll
    for(int nt=0;nt<2;nt++)
      bfr4[kc][nt] = *(const short8*)(Wo + (size_t)(bc0+nt*16+ln)*DH_ + kc*32 + qd*8);
  }
  f32x4 y[2][2];
  #pragma unroll
  for(int mt=0;mt<2;mt++)
    #pragma unroll
    for(int nt=0;nt<2;nt++) y[mt][nt] = (f32x4){0.f,0.f,0.f,0.f};
  #pragma unroll
  for(int kc=0;kc<4;kc++)
    #pragma unroll
    for(int mt=0;mt<2;mt++)
      #pragma unroll
      for(int nt=0;nt<2;nt++)
        y[mt][nt] = __builtin_amdgcn_mfma_f32_16x16x32_bf16(afr[kc][mt], bfr4[kc][nt], y[mt][nt], 0, 0, 0);

  float sS[2][4] = {}, sQ[2][4] = {};
  #pragma unroll
  for(int mt=0;mt<2;mt++){
    #pragma unroll
    for(int nt=0;nt<2;nt++){
      float bv = bo[bc0 + nt*16 + ln];
      #pragma unroll
      for(int r=0;r<4;r++){
        float v = y[mt][nt][r] + bv + resv[mt][nt][r];
        y[mt][nt][r] = v;
        sS[mt][r] += v;
        sQ[mt][r] += v*v;
      }
    }
  }
  #pragma unroll
  for(int mt=0;mt<2;mt++)
    #pragma unroll
    for(int r=0;r<4;r++){
      float a = sS[mt][r], b = sQ[mt][r];
      a += __shfl_xor(a,1); a += __shfl_xor(a,2); a += __shfl_xor(a,4); a += __shfl_xor(a,8);
      b += __shfl_xor(b,1); b += __shfl_xor(b,2); b += __shfl_xor(b,4); b += __shfl_xor(b,8);
      sS[mt][r] = a; sQ[mt][r] = b;
    }
  if(ln == 0){
    #pragma unroll
    for(int mt=0;mt<2;mt++)
      #pragma unroll
      for(int r=0;r<4;r++){
        int row = mt*16 + qd*4 + r;
        redS[w][row] = sS[mt][r];
        redQ[w][row] = sQ[mt][r];
      }
  }
  __syncthreads();
  float mu[2][4], iv[2][4];
  #pragma unroll
  for(int mt=0;mt<2;mt++)
    #pragma unroll
    for(int r=0;r<4;r++){
      int row = mt*16 + qd*4 + r;
      float s = 0.f, q = 0.f;
      #pragma unroll
      for(int ww=0;ww<8;ww++){ s += redS[ww][row]; q += redQ[ww][row]; }
      float m_ = s * (1.0f/D_);
      mu[mt][r] = m_;
      iv[mt][r] = rsqrtf(q*(1.0f/D_) - m_*m_ + 1e-6f);
    }
  #pragma unroll
  for(int mt=0;mt<2;mt++){
    #pragma unroll
    for(int nt=0;nt<2;nt++){
      int col = c0 + nt*16 + ln;
      float gg = p.g1[col], bb = p.be1[col];
      #pragma unroll
      for(int r=0;r<4;r++){
        float yy = (y[mt][nt][r] - mu[mt][r]) * iv[mt][r] * gg + bb;
        y[mt][nt][r] = yy;
        X1[(mt*16+qd*4+r)*264 + col] = f2b(yy);
      }
    }
  }
  __syncthreads();

  // --------- phase B: FFN1 + GELU (wave owns 64 cols; reg dbuf pipeline) ----
  {
    const int fc0 = w * 64;
    f32x4 f1[2][4];
    #pragma unroll
    for(int mt=0;mt<2;mt++)
      #pragma unroll
      for(int nt=0;nt<4;nt++) f1[mt][nt] = (f32x4){0.f,0.f,0.f,0.f};
    short8 wb[2][4];
    #pragma unroll
    for(int nt=0;nt<4;nt++)
      wb[0][nt] = *(const short8*)(p.w1 + (size_t)(fc0+nt*16+ln)*D_ + qd*8);
    #pragma unroll
    for(int it = 0; it < 8; it++){
      const int cur = it & 1, nxt = cur ^ 1;
      if(it < 7){
        #pragma unroll
        for(int nt=0;nt<4;nt++)
          wb[nxt][nt] = *(const short8*)(p.w1 + (size_t)(fc0+nt*16+ln)*D_ + (it+1)*32 + qd*8);
      }
      short8 a0 = *(const short8*)&X1[(ln)*264 + it*32 + qd*8];
      short8 a1 = *(const short8*)&X1[(16+ln)*264 + it*32 + qd*8];
      #pragma unroll
      for(int nt=0;nt<4;nt++){
        f1[0][nt] = __builtin_amdgcn_mfma_f32_16x16x32_bf16(a0, wb[cur][nt], f1[0][nt], 0, 0, 0);
        f1[1][nt] = __builtin_amdgcn_mfma_f32_16x16x32_bf16(a1, wb[cur][nt], f1[1][nt], 0, 0, 0);
      }
    }
    #pragma unroll
    for(int mt=0;mt<2;mt++){
      #pragma unroll
      for(int nt=0;nt<4;nt++){
        int col = fc0 + nt*16 + ln;
        float bv = p.bf1[col];
        #pragma unroll
        for(int r=0;r<4;r++){
          float v = f1[mt][nt][r] + bv;
          v = 0.5f*v*(1.0f + erff(v*0.70710678118654752f));
          X2[(mt*16+qd*4+r)*520 + col] = f2b(v);
        }
      }
    }
  }
  __syncthreads();

  // --------- phase C: FFN2 + res + LN2 (wave owns 32 cols; 64k-chunk dbuf) --
  f32x4 f2[2][2];
  #pragma unroll
  for(int mt=0;mt<2;mt++)
    #pragma unroll
    for(int nt=0;nt<2;nt++) f2[mt][nt] = (f32x4){0.f,0.f,0.f,0.f};
  {
    // chunk = 64 k's = 2 k-steps x 2 nt frags = 4 loads
    short8 wb[2][4];   // [stage][ks*2+nt]
    #pragma unroll
    for(int ks=0;ks<2;ks++)
      #pragma unroll
      for(int nt=0;nt<2;nt++)
        wb[0][ks*2+nt] = *(const short8*)(p.w2 + (size_t)(c0+nt*16+ln)*DFF_ + ks*32 + qd*8);
    #pragma unroll
    for(int ch = 0; ch < 8; ch++){
      const int cur = ch & 1, nxt = cur ^ 1;
      if(ch < 7){
        #pragma unroll
        for(int ks=0;ks<2;ks++)
          #pragma unroll
          for(int nt=0;nt<2;nt++)
            wb[nxt][ks*2+nt] = *(const short8*)(p.w2 + (size_t)(c0+nt*16+ln)*DFF_ + (ch+1)*64 + ks*32 + qd*8);
      }
      #pragma unroll
      for(int ks=0;ks<2;ks++){
        int k0 = ch*64 + ks*32;
        short8 a0 = *(const short8*)&X2[(ln)*520 + k0 + qd*8];
        short8 a1 = *(const short8*)&X2[(16+ln)*520 + k0 + qd*8];
        #pragma unroll
        for(int nt=0;nt<2;nt++){
          f2[0][nt] = __builtin_amdgcn_mfma_f32_16x16x32_bf16(a0, wb[cur][ks*2+nt], f2[0][nt], 0, 0, 0);
          f2[1][nt] = __builtin_amdgcn_mfma_f32_16x16x32_bf16(a1, wb[cur][ks*2+nt], f2[1][nt], 0, 0, 0);
        }
      }
    }
  }
  float sS2[2][4] = {}, sQ2[2][4] = {};
  #pragma unroll
  for(int mt=0;mt<2;mt++){
    #pragma unroll
    for(int nt=0;nt<2;nt++){
      int col = c0 + nt*16 + ln;
      float bv = p.bf2[col];
      #pragma unroll
      for(int r=0;r<4;r++){
        float v = f2[mt][nt][r] + bv + y[mt][nt][r];   // residual = LN1 out (regs)
        f2[mt][nt][r] = v;
        sS2[mt][r] += v;
        sQ2[mt][r] += v*v;
      }
    }
  }
  #pragma unroll
  for(int mt=0;mt<2;mt++)
    #pragma unroll
    for(int r=0;r<4;r++){
      float a = sS2[mt][r], b = sQ2[mt][r];
      a += __shfl_xor(a,1); a += __shfl_xor(a,2); a += __shfl_xor(a,4); a += __shfl_xor(a,8);
      b += __shfl_xor(b,1); b += __shfl_xor(b,2); b += __shfl_xor(b,4); b += __shfl_xor(b,8);
      sS2[mt][r] = a; sQ2[mt][r] = b;
    }
  if(ln == 0){
    #pragma unroll
    for(int mt=0;mt<2;mt++)
      #pragma unroll
      for(int r=0;r<4;r++){
        int row = mt*16 + qd*4 + r;
        redS[w][row] = sS2[mt][r];
        redQ[w][row] = sQ2[mt][r];
      }
  }
  __syncthreads();
  #pragma unroll
  for(int mt=0;mt<2;mt++)
    #pragma unroll
    for(int r=0;r<4;r++){
      int row = mt*16 + qd*4 + r;
      float s = 0.f, q = 0.f;
      #pragma unroll
      for(int ww=0;ww<8;ww++){ s += redS[ww][row]; q += redQ[ww][row]; }
      float m_ = s * (1.0f/D_);
      mu[mt][r] = m_;
      iv[mt][r] = rsqrtf(q*(1.0f/D_) - m_*m_ + 1e-6f);
    }
  #pragma unroll
  for(int mt=0;mt<2;mt++){
    #pragma unroll
    for(int nt=0;nt<2;nt++){
      int col = c0 + nt*16 + ln;
      float gg = p.g2[col], bb = p.be2[col];
      #pragma unroll
      for(int r=0;r<4;r++){
        float yy = (f2[mt][nt][r] - mu[mt][r]) * iv[mt][r] * gg + bb;
        size_t idx = (size_t)(m0 + mt*16 + qd*4 + r)*D_ + col;
        p.h[idx] = yy;
        p.h_bf[idx] = f2b(yy);
      }
    }
  }
}

// ---------------- pooled[b,n,:] = (amm[b,n,:] @ h[b]) / sum_atoms -----------
__global__ __launch_bounds__(256) void pool_kernel(
    const float* __restrict__ amm, const float* __restrict__ sum_atoms,
    const float* __restrict__ h, u16* __restrict__ pooled_bf)
{
  __shared__ float as[S_];
  int bn = blockIdx.x;
  int b  = bn >> 5;
  int t  = threadIdx.x;
  if(t < S_) as[t] = amm[(size_t)bn*S_ + t];
  __syncthreads();
  float acc = 0.f;
  const float* hb = h + (size_t)b*S_*D_ + t;
  #pragma unroll 4
  for(int s = 0; s < S_; s++) acc = fmaf(as[s], hb[(size_t)s*D_], acc);
  pooled_bf[(size_t)bn*D_ + t] = f2b(acc / sum_atoms[bn]);
}

// ============================ host-side launcher ============================
extern "C" void kernel_launch(void* const* d_in, const int* in_sizes, int n_in,
                              void* d_out, int out_size, void* d_ws, size_t ws_size,
                              hipStream_t stream)
{
  const float* x     = (const float*)d_in[0];
  const float* adj   = (const float*)d_in[1];
  const float* dist  = (const float*)d_in[2];
  const float* amm   = (const float*)d_in[3];
  const float* sum_a = (const float*)d_in[4];
  const float* embW  = (const float*)d_in[5];
  const float* embB  = (const float*)d_in[6];
  const float* globW = (const float*)d_in[7];
  const float* globB = (const float*)d_in[8];
  const float* Wq1 = (const float*)d_in[9],  *Wk1 = (const float*)d_in[10],
             *Wv1 = (const float*)d_in[11], *Wo1 = (const float*)d_in[12],
             *Wq2 = (const float*)d_in[13], *Wk2 = (const float*)d_in[14],
             *Wv2 = (const float*)d_in[15], *Wo2 = (const float*)d_in[16];
  const float* bq1 = (const float*)d_in[17], *bk1 = (const float*)d_in[18],
             *bv1 = (const float*)d_in[19], *bo1 = (const float*)d_in[20],
             *bq2 = (const float*)d_in[21], *bk2 = (const float*)d_in[22],
             *bv2 = (const float*)d_in[23], *bo2 = (const float*)d_in[24];
  const float* Wf1 = (const float*)d_in[25], *bf1 = (const float*)d_in[26],
             *Wf2 = (const float*)d_in[27], *bf2 = (const float*)d_in[28],
             *g1  = (const float*)d_in[29], *be1 = (const float*)d_in[30],
             *g2  = (const float*)d_in[31], *be2 = (const float*)d_in[32];

  float* wsf = (float*)d_ws;
  float* h     = wsf; wsf += (size_t)MS_*D_;
  float* maskb = wsf; wsf += MS_;
  // bf16 region
  u16* bb = (u16*)wsf;
  u16* adjm16  = bb; bb += (size_t)B_*S_*S_;
  u16* distr16 = bb; bb += (size_t)B_*S_*S_;
  u16* o1_bf   = bb; bb += (size_t)MS_*DH_;
  u16* o2_bf   = bb; bb += (size_t)MS_*DH_;
  u16* h_bf    = bb; bb += (size_t)MS_*D_;
  u16* pooled_bf = bb; bb += (size_t)B_*NSUB_*D_;
  u16* globWt  = bb; bb += (size_t)D_*D_;
  u16* wq1t = bb; bb += (size_t)L_*DH_*DH_;
  u16* wk1t = bb; bb += (size_t)L_*DH_*DH_;
  u16* wv1t = bb; bb += (size_t)L_*DH_*DH_;
  u16* wo1t = bb; bb += (size_t)L_*DH_*DH_;
  u16* wq2t = bb; bb += (size_t)L_*DH_*DH_;
  u16* wk2t = bb; bb += (size_t)L_*DH_*DH_;
  u16* wv2t = bb; bb += (size_t)L_*DH_*DH_;
  u16* wo2t = bb; bb += (size_t)L_*DH_*DH_;
  u16* wf1t = bb; bb += (size_t)L_*D_*DFF_;       // [L][512][256]
  u16* wf2t = bb; bb += (size_t)L_*DFF_*D_;       // [L][256][512]

  embed_kernel<<<MS_/4, 256, 0, stream>>>(x, embW, embB, h, h_bf, maskb);
  adjrescale_kernel<<<(B_*S_*S_)/256, 256, 0, stream>>>(adj, dist, maskb, adjm16, distr16);
  {
    TDs td;
    const float* S8[8] = {Wq1, Wk1, Wv1, Wo1, Wq2, Wk2, Wv2, Wo2};
    u16* D8[8] = {wq1t, wk1t, wv1t, wo1t, wq2t, wk2t, wv2t, wo2t};
    for(int i = 0; i < 8; i++) td.d[i] = {S8[i], D8[i], DH_, DH_, L_};
    td.d[8]  = {Wf1, wf1t, D_, DFF_, L_};
    td.d[9]  = {Wf2, wf2t, DFF_, D_, L_};
    td.d[10] = {globW, globWt, D_, D_, 1};
    transpose_all_kernel<<<dim3(16,16,11), dim3(32,8), 0, stream>>>(td);
  }

  for(int l = 0; l < L_; l++){
    QAArgs a1 = { wq1t + (size_t)l*DH_*DH_, wk1t + (size_t)l*DH_*DH_, wv1t + (size_t)l*DH_*DH_,
                  bq1 + (size_t)l*DH_, bk1 + (size_t)l*DH_, bv1 + (size_t)l*DH_ };
    QAArgs a2 = { wq2t + (size_t)l*DH_*DH_, wk2t + (size_t)l*DH_*DH_, wv2t + (size_t)l*DH_*DH_,
                  bq2 + (size_t)l*DH_, bk2 + (size_t)l*DH_, bv2 + (size_t)l*DH_ };
    qkv_attn_kernel<<<dim3(B_*H_, 2), 256, 0, stream>>>(h_bf, a1, a2, adjm16, distr16, maskb,
                                                        o1_bf, o2_bf);
    TailArgs ta;
    ta.o1 = o1_bf; ta.o2 = o2_bf;
    ta.wo1 = wo1t + (size_t)l*DH_*DH_; ta.wo2 = wo2t + (size_t)l*DH_*DH_;
    ta.w1 = wf1t + (size_t)l*D_*DFF_;  ta.w2 = wf2t + (size_t)l*DFF_*D_;
    ta.bo1 = bo1 + (size_t)l*DH_; ta.bo2 = bo2 + (size_t)l*DH_;
    ta.bf1 = bf1 + (size_t)l*DFF_; ta.bf2 = bf2 + (size_t)l*D_;
    ta.g1 = g1 + (size_t)l*D_; ta.be1 = be1 + (size_t)l*D_;
    ta.g2 = g2 + (size_t)l*D_; ta.be2 = be2 + (size_t)l*D_;
    ta.h = h; ta.h_bf = h_bf;
    tail_kernel<<<MS_/32, 512, 0, stream>>>(ta);
  }

  pool_kernel<<<B_*NSUB_, 256, 0, stream>>>(amm, sum_a, h, pooled_bf);
  // final: relu(pooled @ glob_W + glob_b), M=2048 N=256 K=256
  {
    MG6 a;
    a.g[0].A = pooled_bf; a.g[0].W = globWt;
    a.g[0].bias = globB; a.g[0].C = (float*)d_out;
    a.g[0].lda = D_; a.g[0].K = D_; a.g[0].ldc = D_;
    a.g[0].aofs = 0; a.g[0].cofs = 0;
    mgemm_kernel<64,false,1><<<dim3((B_*NSUB_)/64, D_/128, 1), 256, 0, stream>>>(a);
  }
}